// Round 14
// baseline (958.677 us; speedup 1.0000x reference)
//
#include <hip/hip_runtime.h>
#include <hip/hip_bf16.h>
#include <string.h>

typedef __hip_bfloat16 bf16;
typedef short v8s __attribute__((ext_vector_type(8)));
typedef short v4s __attribute__((ext_vector_type(4)));
typedef float v4f __attribute__((ext_vector_type(4)));

#define H_ 128
#define P_ 6
#define K_ 4
#define NBR_CAP 48

__device__ __forceinline__ float ldf(const float* p, size_t i) { return p[i]; }
__device__ __forceinline__ float ldf(const bf16* p, size_t i) { return __bfloat162float(p[i]); }

__device__ __forceinline__ float s2f(short s) {
    unsigned int u = ((unsigned int)(unsigned short)s) << 16;
    float f; __builtin_memcpy(&f, &u, 4); return f;
}
__device__ __forceinline__ short f2s(float v) {
    bf16 h = __float2bfloat16(v);
    short s; __builtin_memcpy(&s, &h, 2); return s;
}
__device__ __forceinline__ v4f MFMA(v8s a, v8s b, v4f c) {
    return __builtin_amdgcn_mfma_f32_16x16x32_bf16(a, b, c, 0, 0, 0);
}

// ---------------- CSR build: neighbor u8 lists + degree + float rowsum ----------------
__global__ __launch_bounds__(128) void k_csr(const float* __restrict__ adj,
    unsigned char* __restrict__ nbr, int* __restrict__ deg, float* __restrict__ degf)
{
    const int gi = blockIdx.x * 128 + threadIdx.x;   // (g,i), 4096 rows
    const float* row = adj + (size_t)gi * 128;
    unsigned char* nb = nbr + (size_t)gi * NBR_CAP;
    int c = 0; float s = 0.f;
    for (int j = 0; j < 128; ++j) {
        float a = row[j];
        if (a != 0.f) { s += a; if (c < NBR_CAP) nb[c] = (unsigned char)j; ++c; }
    }
    deg[gi] = (c < NBR_CAP) ? c : NBR_CAP;
    degf[gi] = s;
}

// ---------------- adjacency -> bf16 (values are exactly 0/1) ----------------
__global__ __launch_bounds__(128) void k_adjb(const float* __restrict__ adj, bf16* __restrict__ adjb)
{
    const size_t i = (size_t)blockIdx.x * 128 + threadIdx.x;
    adjb[i] = __float2bfloat16(adj[i]);
}

// ---------------- transpose 8 (128x128) weights to bf16 WT[n][k] ----------------
__global__ __launch_bounds__(128) void k_wt8(
    const float* s0, const float* s1, const float* s2, const float* s3,
    const float* s4, const float* s5, const float* s6, const float* s7,
    bf16* __restrict__ dst)
{
    const int w = blockIdx.x >> 7, n = blockIdx.x & 127, k = threadIdx.x;
    const float* arr[8] = {s0, s1, s2, s3, s4, s5, s6, s7};
    dst[(size_t)w * 16384 + n * 128 + k] = __float2bfloat16(arr[w][k * 128 + n]);
}

// ---------------- transpose single 128x128 weight to bf16 ----------------
__global__ __launch_bounds__(128) void k_wt1(const float* __restrict__ src, bf16* __restrict__ dst)
{
    const int n = blockIdx.x, k = threadIdx.x;
    dst[n * 128 + k] = __float2bfloat16(src[k * 128 + n]);
}

// ---------------- input embedding: t1 = relu(x * W1 + b1) ----------------
__global__ __launch_bounds__(128) void k_in_t1(const float* __restrict__ x,
    const float* __restrict__ W1, const float* __restrict__ b1, float* __restrict__ t1)
{
    int r = blockIdx.x, hd = threadIdx.x;
    t1[(size_t)r * H_ + hd] = fmaxf(fmaf(x[r], W1[hd], b1[hd]), 0.f);
}

// ---------------- generic VALU fused block (used for small row counts) ----------------
template<bool DO_MM1, bool HAS_RES>
__global__ __launch_bounds__(128) void k_block(
    const float* __restrict__ in, const float* __restrict__ res, float* __restrict__ out,
    const float* __restrict__ W1, const float* __restrict__ b1,
    const float* __restrict__ W2, const float* __restrict__ b2,
    const float* __restrict__ gam, const float* __restrict__ bet)
{
    __shared__ float sA[16][136];
    __shared__ float sB[16][136];
    __shared__ float sStat[32];
    const int hd = threadIdx.x;
    const size_t row0 = (size_t)blockIdx.x * 16;
    #pragma unroll
    for (int r = 0; r < 16; ++r) sA[r][hd] = in[(row0 + r) * H_ + hd];
    __syncthreads();
    float acc[16];
    if (DO_MM1) {
        #pragma unroll
        for (int r = 0; r < 16; ++r) acc[r] = b1[hd];
        for (int k = 0; k < H_; k += 4) {
            float w0 = W1[(k+0)*H_+hd], w1 = W1[(k+1)*H_+hd], w2 = W1[(k+2)*H_+hd], w3 = W1[(k+3)*H_+hd];
            #pragma unroll
            for (int r = 0; r < 16; ++r) {
                float4 a = *(const float4*)&sA[r][k];
                acc[r] = fmaf(a.x, w0, acc[r]); acc[r] = fmaf(a.y, w1, acc[r]);
                acc[r] = fmaf(a.z, w2, acc[r]); acc[r] = fmaf(a.w, w3, acc[r]);
            }
        }
        #pragma unroll
        for (int r = 0; r < 16; ++r) sB[r][hd] = fmaxf(acc[r], 0.f);
    } else {
        #pragma unroll
        for (int r = 0; r < 16; ++r) sB[r][hd] = sA[r][hd];
    }
    __syncthreads();
    #pragma unroll
    for (int r = 0; r < 16; ++r) acc[r] = b2[hd];
    for (int k = 0; k < H_; k += 4) {
        float w0 = W2[(k+0)*H_+hd], w1 = W2[(k+1)*H_+hd], w2 = W2[(k+2)*H_+hd], w3 = W2[(k+3)*H_+hd];
        #pragma unroll
        for (int r = 0; r < 16; ++r) {
            float4 a = *(const float4*)&sB[r][k];
            acc[r] = fmaf(a.x, w0, acc[r]); acc[r] = fmaf(a.y, w1, acc[r]);
            acc[r] = fmaf(a.z, w2, acc[r]); acc[r] = fmaf(a.w, w3, acc[r]);
        }
    }
    __syncthreads();
    #pragma unroll
    for (int r = 0; r < 16; ++r) sA[r][hd] = acc[r];
    __syncthreads();
    if (hd < 16) {
        float s = 0.f, ss = 0.f;
        for (int k = 0; k < H_; ++k) { float v = sA[hd][k]; s += v; ss += v * v; }
        float mean = s * (1.f / H_);
        float var = ss * (1.f / H_) - mean * mean;
        sStat[hd] = mean; sStat[16 + hd] = rsqrtf(var + 1e-5f);
    }
    __syncthreads();
    float gv = gam[hd], bv = bet[hd];
    #pragma unroll
    for (int r = 0; r < 16; ++r) {
        float v = fmaxf((acc[r] - sStat[r]) * sStat[16 + r] * gv + bv, 0.f);
        if (HAS_RES) v += res[(row0 + r) * H_ + hd];
        out[(row0 + r) * H_ + hd] = v;
    }
}

// ---------------- gemm + bias + relu ----------------
template<bool GATHER, typename T>
__global__ __launch_bounds__(128) void k_gemm_relu(
    const T* __restrict__ in, const float* __restrict__ res, float* __restrict__ out,
    const float* __restrict__ W, const float* __restrict__ b)
{
    __shared__ float sA[16][136];
    const int hd = threadIdx.x;
    const size_t row0 = (size_t)blockIdx.x * 16;
    #pragma unroll
    for (int r = 0; r < 16; ++r) sA[r][hd] = ldf(in, (row0 + r) * H_ + hd);
    __syncthreads();
    float acc[16];
    #pragma unroll
    for (int r = 0; r < 16; ++r) acc[r] = b[hd];
    for (int k = 0; k < H_; k += 4) {
        float w0 = W[(k+0)*H_+hd], w1 = W[(k+1)*H_+hd], w2 = W[(k+2)*H_+hd], w3 = W[(k+3)*H_+hd];
        #pragma unroll
        for (int r = 0; r < 16; ++r) {
            float4 a = *(const float4*)&sA[r][k];
            acc[r] = fmaf(a.x, w0, acc[r]); acc[r] = fmaf(a.y, w1, acc[r]);
            acc[r] = fmaf(a.z, w2, acc[r]); acc[r] = fmaf(a.w, w3, acc[r]);
        }
    }
    #pragma unroll
    for (int r = 0; r < 16; ++r) {
        size_t rr = row0 + r;
        float v = fmaxf(acc[r], 0.f);
        if (GATHER) {
            int i = (int)(rr & 127);
            int g = (int)(rr >> 11);
            v += res[((size_t)(g * 128 + i)) * H_ + hd];
        }
        out[rr * H_ + hd] = v;
    }
}

// ---------------- dense sparse-matvec for g-layers (small, keep VALU) ----------------
__global__ __launch_bounds__(128) void k_spmv(const float* __restrict__ adj,
    const float* __restrict__ xin, float* __restrict__ mout, int subShift)
{
    __shared__ float sAdj[128];
    const int hd = threadIdx.x;
    const int bi = blockIdx.x;
    const int bb = bi >> 7, i = bi & 127;
    const int g = bb >> subShift;
    sAdj[hd] = adj[((size_t)(g * 128 + i)) * 128 + hd];
    __syncthreads();
    float acc = 0.f;
    const float* xb = xin + (size_t)bb * 128 * H_ + hd;
    for (int j = 0; j < 128; ++j) {
        float a = sAdj[j];
        if (a != 0.f) acc = fmaf(a, xb[(size_t)j * H_], acc);
    }
    mout[(size_t)bi * H_ + hd] = acc;
}

// ---------------- ID layers 1+2 FULLY FUSED: per subgraph, loop p:
//   m-tile (closed form, VALU) -> id1 MM1/MM2/LN (+1, patch) -> z in regs (zs) ->
//   residual macc += zs -> scatter z^T -> spmv M=A@Z (MFMA) -> id2 MM1/MM2/LN -> macc.
// z2t NEVER materialized (kills 98 MB write + 59 MB read + one 155 us kernel).
// Single LDS buffer sB (v9 discipline), 4 barriers/p. Numerics chain identical to
// id1_fused + id2_v9 (same rounding order incl. patch f2s(s2f(f2s(v+1))+e)).
__global__ __launch_bounds__(256) void k_id12(
    const float* __restrict__ adj, const float* __restrict__ degf,
    const bf16* __restrict__ adjb, const int* __restrict__ num_node,
    const int* __restrict__ subgs, const int* __restrict__ allperm,
    const float* __restrict__ idemb, bf16* __restrict__ zm,
    const bf16* __restrict__ WT,          // i1.W1t, i1.W2t, i2.W1t, i2.W2t (4 x 16384)
    const float* __restrict__ ib1, const float* __restrict__ ib2,
    const float* __restrict__ ig, const float* __restrict__ ibn)
{
    __shared__ __align__(16) short sB[128][136];   // m / T1 / Z^T / M / T2   34.8 KB
    __shared__ float sP[8][128];                   // i1{b1,b2,g,bn}, i2{...}  4.0 KB
    __shared__ float sE[K_][128];                  // idemb[perm]-1 rows       2.0 KB
    const int t = threadIdx.x;
    const int b_s = blockIdx.x;
    const int g = b_s >> 4;
    const int wave = t >> 6, lane = t & 63, quad = lane >> 4, l16 = lane & 15;
    const int wrow = wave << 5;

    // params -> LDS (4 elems/thread)
    #pragma unroll
    for (int u = 0; u < 4; ++u) {
        const int v = t + u * 256;
        const int a = v >> 7, n = v & 127;
        const float* src = (a == 0) ? ib1 : (a == 1) ? ib2 : (a == 2) ? ig : (a == 3) ? ibn
                         : (a == 4) ? ib1 + 128 : (a == 5) ? ib2 + 128
                         : (a == 6) ? ig + 128 : ibn + 128;
        sP[a][n] = src[n];
    }

    // adjacency A-frags for spmv (constant over p)
    v8s aA[2][4];
    {
        const bf16* ar = adjb + (size_t)g * 16384;
        #pragma unroll
        for (int mt = 0; mt < 2; ++mt)
            #pragma unroll
            for (int kk = 0; kk < 4; ++kk)
                aA[mt][kk] = *(const v8s*)(ar + (size_t)(wrow + mt * 16 + l16) * 128 + kk * 32 + quad * 8);
    }
    int nodeq[K_];
    #pragma unroll
    for (int q = 0; q < K_; ++q) nodeq[q] = subgs[b_s * K_ + q];

    // m-tile per-thread constants (p-invariant): row mi, cols [mhalf, mhalf+64)
    const int mi = t >> 1, mhalf = (t & 1) * 64;
    const int gmi = g * 128 + mi;
    const float dg = degf[gmi];
    float aqm[K_];
    #pragma unroll
    for (int q = 0; q < K_; ++q) aqm[q] = adj[(size_t)gmi * 128 + nodeq[q]];

    float macc[2][8][4];
    #pragma unroll
    for (int mt = 0; mt < 2; ++mt)
        #pragma unroll
        for (int nt = 0; nt < 8; ++nt)
            #pragma unroll
            for (int r = 0; r < 4; ++r) macc[mt][nt][r] = 0.f;

    for (int p = 0; p < P_; ++p) {
        // ---- stage sE (idemb[perm]-1) for this p ----
        for (int u = t; u < K_ * 128; u += 256) {
            const int q = u >> 7, f = u & 127;
            sE[q][f] = idemb[(size_t)allperm[q * P_ + p] * H_ + f] - 1.f;
        }
        __syncthreads();   // (a) sE + sP visible; prev-p cross-wave sB reads already fenced
        // ---- m-tile into sB wave-own rows (vectorized 8-wide) ----
        #pragma unroll
        for (int fb = 0; fb < 64; fb += 8) {
            v8s pk;
            #pragma unroll
            for (int e = 0; e < 8; ++e) {
                float v = dg;
                #pragma unroll
                for (int q = 0; q < K_; ++q) v = fmaf(aqm[q], sE[q][mhalf + fb + e], v);
                pk[e] = f2s(v);
            }
            *(v8s*)&sB[mi][mhalf + fb] = pk;
        }
        // ---- id1 MM1: T1 = relu(m @ W1 + b1)  (wave-own rows, no barrier) ----
        v4f acc[2][8];
        #pragma unroll
        for (int mt = 0; mt < 2; ++mt)
            #pragma unroll
            for (int nt = 0; nt < 8; ++nt) acc[mt][nt] = (v4f){0.f, 0.f, 0.f, 0.f};
        #pragma unroll
        for (int kk = 0; kk < 4; ++kk) {
            v8s a0 = *(const v8s*)&sB[wrow + l16][kk * 32 + quad * 8];
            v8s a1 = *(const v8s*)&sB[wrow + 16 + l16][kk * 32 + quad * 8];
            #pragma unroll
            for (int nt = 0; nt < 8; ++nt) {
                v8s b = *(const v8s*)(WT + (nt * 16 + l16) * 128 + kk * 32 + quad * 8);
                acc[0][nt] = MFMA(a0, b, acc[0][nt]);
                acc[1][nt] = MFMA(a1, b, acc[1][nt]);
            }
        }
        #pragma unroll
        for (int nt = 0; nt < 8; ++nt) {
            float bb = sP[0][nt * 16 + l16];
            #pragma unroll
            for (int mt = 0; mt < 2; ++mt)
                #pragma unroll
                for (int r = 0; r < 4; ++r)
                    sB[wrow + mt * 16 + quad * 4 + r][nt * 16 + l16] = f2s(fmaxf(acc[mt][nt][r] + bb, 0.f));
        }
        // ---- id1 MM2 ----
        #pragma unroll
        for (int mt = 0; mt < 2; ++mt)
            #pragma unroll
            for (int nt = 0; nt < 8; ++nt) acc[mt][nt] = (v4f){0.f, 0.f, 0.f, 0.f};
        #pragma unroll
        for (int kk = 0; kk < 4; ++kk) {
            v8s a0 = *(const v8s*)&sB[wrow + l16][kk * 32 + quad * 8];
            v8s a1 = *(const v8s*)&sB[wrow + 16 + l16][kk * 32 + quad * 8];
            #pragma unroll
            for (int nt = 0; nt < 8; ++nt) {
                v8s b = *(const v8s*)(WT + 16384 + (nt * 16 + l16) * 128 + kk * 32 + quad * 8);
                acc[0][nt] = MFMA(a0, b, acc[0][nt]);
                acc[1][nt] = MFMA(a1, b, acc[1][nt]);
            }
        }
        // ---- id1 LN -> z (+1, patch), residual accumulate; keep zs packed ----
        v4s zs[2][8];
        #pragma unroll
        for (int mt = 0; mt < 2; ++mt)
            #pragma unroll
            for (int r = 0; r < 4; ++r) {
                float s = 0.f, qq = 0.f;
                #pragma unroll
                for (int nt = 0; nt < 8; ++nt) {
                    float u = acc[mt][nt][r] + sP[1][nt * 16 + l16];
                    acc[mt][nt][r] = u;
                    s += u; qq += u * u;
                }
                #pragma unroll
                for (int d = 1; d < 16; d <<= 1) {
                    s += __shfl_xor(s, d);
                    qq += __shfl_xor(qq, d);
                }
                float mn = s * (1.f / 128.f);
                float rs = rsqrtf(qq * (1.f / 128.f) - mn * mn + 1e-5f);
                const int i = wrow + mt * 16 + quad * 4 + r;
                int eq = -1;
                #pragma unroll
                for (int q = 0; q < K_; ++q) if (nodeq[q] == i) eq = q;
                #pragma unroll
                for (int nt = 0; nt < 8; ++nt) {
                    const int n = nt * 16 + l16;
                    float v = fmaxf((acc[mt][nt][r] - mn) * rs * sP[2][n] + sP[3][n], 0.f);
                    short z = f2s(v + 1.0f);
                    if (eq >= 0) z = f2s(s2f(z) + sE[eq][n]);
                    macc[mt][nt][r] += s2f(z);
                    zs[mt][nt][r] = z;
                }
            }
        __syncthreads();   // (b) all waves done reading sB as T1
        // ---- scatter Z^T: sB[n][i] (8-byte vector per (mt,nt)) ----
        #pragma unroll
        for (int mt = 0; mt < 2; ++mt) {
            const int i0 = wrow + mt * 16 + quad * 4;
            #pragma unroll
            for (int nt = 0; nt < 8; ++nt)
                *(v4s*)&sB[nt * 16 + l16][i0] = zs[mt][nt];
        }
        __syncthreads();   // (d) Z^T complete
        // ---- spmv: M = A @ Z ----
        #pragma unroll
        for (int mt = 0; mt < 2; ++mt)
            #pragma unroll
            for (int nt = 0; nt < 8; ++nt) acc[mt][nt] = (v4f){0.f, 0.f, 0.f, 0.f};
        #pragma unroll
        for (int kk = 0; kk < 4; ++kk)
            #pragma unroll
            for (int nt = 0; nt < 8; ++nt) {
                v8s b = *(const v8s*)&sB[nt * 16 + l16][kk * 32 + quad * 8];
                acc[0][nt] = MFMA(aA[0][kk], b, acc[0][nt]);
                acc[1][nt] = MFMA(aA[1][kk], b, acc[1][nt]);
            }
        __syncthreads();   // (e) spmv reads done; sB reusable as M/T2
        #pragma unroll
        for (int nt = 0; nt < 8; ++nt)
            #pragma unroll
            for (int mt = 0; mt < 2; ++mt)
                #pragma unroll
                for (int r = 0; r < 4; ++r)
                    sB[wrow + mt * 16 + quad * 4 + r][nt * 16 + l16] = f2s(acc[mt][nt][r]);
        // ---- id2 MM1 ----
        #pragma unroll
        for (int mt = 0; mt < 2; ++mt)
            #pragma unroll
            for (int nt = 0; nt < 8; ++nt) acc[mt][nt] = (v4f){0.f, 0.f, 0.f, 0.f};
        #pragma unroll
        for (int kk = 0; kk < 4; ++kk) {
            v8s a0 = *(const v8s*)&sB[wrow + l16][kk * 32 + quad * 8];
            v8s a1 = *(const v8s*)&sB[wrow + 16 + l16][kk * 32 + quad * 8];
            #pragma unroll
            for (int nt = 0; nt < 8; ++nt) {
                v8s b = *(const v8s*)(WT + 2 * 16384 + (nt * 16 + l16) * 128 + kk * 32 + quad * 8);
                acc[0][nt] = MFMA(a0, b, acc[0][nt]);
                acc[1][nt] = MFMA(a1, b, acc[1][nt]);
            }
        }
        #pragma unroll
        for (int nt = 0; nt < 8; ++nt) {
            float bb = sP[4][nt * 16 + l16];
            #pragma unroll
            for (int mt = 0; mt < 2; ++mt)
                #pragma unroll
                for (int r = 0; r < 4; ++r)
                    sB[wrow + mt * 16 + quad * 4 + r][nt * 16 + l16] = f2s(fmaxf(acc[mt][nt][r] + bb, 0.f));
        }
        // ---- id2 MM2 ----
        #pragma unroll
        for (int mt = 0; mt < 2; ++mt)
            #pragma unroll
            for (int nt = 0; nt < 8; ++nt) acc[mt][nt] = (v4f){0.f, 0.f, 0.f, 0.f};
        #pragma unroll
        for (int kk = 0; kk < 4; ++kk) {
            v8s a0 = *(const v8s*)&sB[wrow + l16][kk * 32 + quad * 8];
            v8s a1 = *(const v8s*)&sB[wrow + 16 + l16][kk * 32 + quad * 8];
            #pragma unroll
            for (int nt = 0; nt < 8; ++nt) {
                v8s b = *(const v8s*)(WT + 3 * 16384 + (nt * 16 + l16) * 128 + kk * 32 + quad * 8);
                acc[0][nt] = MFMA(a0, b, acc[0][nt]);
                acc[1][nt] = MFMA(a1, b, acc[1][nt]);
            }
        }
        // ---- id2 bias2, LN, relu, p-mean accumulate ----
        #pragma unroll
        for (int mt = 0; mt < 2; ++mt)
            #pragma unroll
            for (int r = 0; r < 4; ++r) {
                float s = 0.f, qq = 0.f;
                #pragma unroll
                for (int nt = 0; nt < 8; ++nt) {
                    float u = acc[mt][nt][r] + sP[5][nt * 16 + l16];
                    acc[mt][nt][r] = u;
                    s += u; qq += u * u;
                }
                #pragma unroll
                for (int d = 1; d < 16; d <<= 1) {
                    s += __shfl_xor(s, d);
                    qq += __shfl_xor(qq, d);
                }
                float mn = s * (1.f / 128.f);
                float rs = rsqrtf(qq * (1.f / 128.f) - mn * mn + 1e-5f);
                #pragma unroll
                for (int nt = 0; nt < 8; ++nt) {
                    const int n = nt * 16 + l16;
                    macc[mt][nt][r] += fmaxf((acc[mt][nt][r] - mn) * rs * sP[6][n] + sP[7][n], 0.f);
                }
            }
        // no trailing barrier: next p's first cross-wave op (sE stage -> bar (a))
    }
    // ---- write zm = masked p-mean ----
    const int nn = num_node[g];
    #pragma unroll
    for (int mt = 0; mt < 2; ++mt)
        #pragma unroll
        for (int nt = 0; nt < 8; ++nt)
            #pragma unroll
            for (int r = 0; r < 4; ++r) {
                const int i = wrow + mt * 16 + quad * 4 + r;
                const int n = nt * 16 + l16;
                float v = (i >= nn) ? 0.f : macc[mt][nt][r] * (1.f / 6.f);
                zm[((size_t)(b_s * 128 + i)) * 128 + n] = __float2bfloat16(v);
            }
}

// ---------------- fused gl stage: setmlp1 + 2 gl layers + node-sum (passing, R11) ----------------
__global__ __launch_bounds__(256) void k_gl_fused(
    const bf16* __restrict__ zm, const float* __restrict__ hb,
    const bf16* __restrict__ adjb,
    const bf16* __restrict__ s1Wt, const float* __restrict__ s1_b,
    const bf16* __restrict__ WTgl,          // glW1t[0], glW2t[0], glW1t[1], glW2t[1]
    const float* __restrict__ glb1, const float* __restrict__ glb2,
    const float* __restrict__ glg, const float* __restrict__ glbn,
    float* __restrict__ hsum)
{
    __shared__ __align__(16) short sHsT[128][136];  // Hs^T bf16 [f][node]  34.8 KB
    __shared__ __align__(16) short sM[128][136];    // M / T scratch        34.8 KB (reused as f32 sRed)
    __shared__ float sP[9][128];                    // gl biases x2 + s1_b   4.5 KB
    const int t = threadIdx.x;
    const int b_s = blockIdx.x;
    const int g = b_s >> 4;
    const int wave = t >> 6, lane = t & 63, quad = lane >> 4, l16 = lane & 15;
    const int wrow = wave << 5;

    for (int u = t; u < 9 * 128; u += 256) {
        const int a = u >> 7, n = u & 127;
        const float* src =
            (a == 0) ? glb1 : (a == 1) ? glb2 : (a == 2) ? glg : (a == 3) ? glbn :
            (a == 4) ? glb1 + 128 : (a == 5) ? glb2 + 128 : (a == 6) ? glg + 128 :
            (a == 7) ? glbn + 128 : s1_b;
        sP[a][n] = src[n];
    }

    v8s aA[2][4];
    {
        const bf16* ar = adjb + (size_t)g * 16384;
        #pragma unroll
        for (int mt = 0; mt < 2; ++mt)
            #pragma unroll
            for (int kk = 0; kk < 4; ++kk)
                aA[mt][kk] = *(const v8s*)(ar + (size_t)(wrow + mt * 16 + l16) * 128 + kk * 32 + quad * 8);
    }

    // ---- setmlp1: hs = relu(zm @ s1W + s1b) + h[g] ----
    v4f acc[2][8];
    #pragma unroll
    for (int mt = 0; mt < 2; ++mt)
        #pragma unroll
        for (int nt = 0; nt < 8; ++nt) acc[mt][nt] = (v4f){0.f, 0.f, 0.f, 0.f};
    #pragma unroll
    for (int kk = 0; kk < 4; ++kk) {
        v8s a0 = *(const v8s*)(zm + ((size_t)(b_s * 128) + wrow + l16) * 128 + kk * 32 + quad * 8);
        v8s a1 = *(const v8s*)(zm + ((size_t)(b_s * 128) + wrow + 16 + l16) * 128 + kk * 32 + quad * 8);
        #pragma unroll
        for (int nt = 0; nt < 8; ++nt) {
            v8s b = *(const v8s*)(s1Wt + (nt * 16 + l16) * 128 + kk * 32 + quad * 8);
            acc[0][nt] = MFMA(a0, b, acc[0][nt]);
            acc[1][nt] = MFMA(a1, b, acc[1][nt]);
        }
    }
    __syncthreads();
    float hs_reg[2][8][4];
    #pragma unroll
    for (int mt = 0; mt < 2; ++mt)
        #pragma unroll
        for (int nt = 0; nt < 8; ++nt)
            #pragma unroll
            for (int r = 0; r < 4; ++r) {
                const int i = wrow + mt * 16 + quad * 4 + r;
                const int n = nt * 16 + l16;
                float v = fmaxf(acc[mt][nt][r] + sP[8][n], 0.f);
                v += hb[((size_t)(g * 128 + i)) * 128 + n];
                hs_reg[mt][nt][r] = v;
                sHsT[n][i] = f2s(v);
            }
    __syncthreads();

    for (int l = 0; l < 2; ++l) {
        const bf16* W1t = WTgl + (size_t)(2 * l) * 16384;
        const bf16* W2t = WTgl + (size_t)(2 * l + 1) * 16384;
        #pragma unroll
        for (int mt = 0; mt < 2; ++mt)
            #pragma unroll
            for (int nt = 0; nt < 8; ++nt) acc[mt][nt] = (v4f){0.f, 0.f, 0.f, 0.f};
        #pragma unroll
        for (int kk = 0; kk < 4; ++kk)
            #pragma unroll
            for (int nt = 0; nt < 8; ++nt) {
                v8s b = *(const v8s*)&sHsT[nt * 16 + l16][kk * 32 + quad * 8];
                acc[0][nt] = MFMA(aA[0][kk], b, acc[0][nt]);
                acc[1][nt] = MFMA(aA[1][kk], b, acc[1][nt]);
            }
        #pragma unroll
        for (int nt = 0; nt < 8; ++nt)
            #pragma unroll
            for (int mt = 0; mt < 2; ++mt)
                #pragma unroll
                for (int r = 0; r < 4; ++r)
                    sM[wrow + mt * 16 + quad * 4 + r][nt * 16 + l16] = f2s(acc[mt][nt][r]);
        __syncthreads();
        #pragma unroll
        for (int mt = 0; mt < 2; ++mt)
            #pragma unroll
            for (int nt = 0; nt < 8; ++nt) acc[mt][nt] = (v4f){0.f, 0.f, 0.f, 0.f};
        #pragma unroll
        for (int kk = 0; kk < 4; ++kk) {
            v8s a0 = *(const v8s*)&sM[wrow + l16][kk * 32 + quad * 8];
            v8s a1 = *(const v8s*)&sM[wrow + 16 + l16][kk * 32 + quad * 8];
            #pragma unroll
            for (int nt = 0; nt < 8; ++nt) {
                v8s b = *(const v8s*)(W1t + (nt * 16 + l16) * 128 + kk * 32 + quad * 8);
                acc[0][nt] = MFMA(a0, b, acc[0][nt]);
                acc[1][nt] = MFMA(a1, b, acc[1][nt]);
            }
        }
        #pragma unroll
        for (int nt = 0; nt < 8; ++nt) {
            float bb = sP[4 * l + 0][nt * 16 + l16];
            #pragma unroll
            for (int mt = 0; mt < 2; ++mt)
                #pragma unroll
                for (int r = 0; r < 4; ++r)
                    sM[wrow + mt * 16 + quad * 4 + r][nt * 16 + l16] = f2s(fmaxf(acc[mt][nt][r] + bb, 0.f));
        }
        #pragma unroll
        for (int mt = 0; mt < 2; ++mt)
            #pragma unroll
            for (int nt = 0; nt < 8; ++nt) acc[mt][nt] = (v4f){0.f, 0.f, 0.f, 0.f};
        #pragma unroll
        for (int kk = 0; kk < 4; ++kk) {
            v8s a0 = *(const v8s*)&sM[wrow + l16][kk * 32 + quad * 8];
            v8s a1 = *(const v8s*)&sM[wrow + 16 + l16][kk * 32 + quad * 8];
            #pragma unroll
            for (int nt = 0; nt < 8; ++nt) {
                v8s b = *(const v8s*)(W2t + (nt * 16 + l16) * 128 + kk * 32 + quad * 8);
                acc[0][nt] = MFMA(a0, b, acc[0][nt]);
                acc[1][nt] = MFMA(a1, b, acc[1][nt]);
            }
        }
        #pragma unroll
        for (int mt = 0; mt < 2; ++mt)
            #pragma unroll
            for (int r = 0; r < 4; ++r) {
                float s = 0.f, qq = 0.f;
                #pragma unroll
                for (int nt = 0; nt < 8; ++nt) {
                    float u = acc[mt][nt][r] + sP[4 * l + 1][nt * 16 + l16];
                    acc[mt][nt][r] = u;
                    s += u; qq += u * u;
                }
                #pragma unroll
                for (int d = 1; d < 16; d <<= 1) {
                    s += __shfl_xor(s, d);
                    qq += __shfl_xor(qq, d);
                }
                float mn = s * (1.f / 128.f);
                float rs = rsqrtf(qq * (1.f / 128.f) - mn * mn + 1e-5f);
                const int i = wrow + mt * 16 + quad * 4 + r;
                #pragma unroll
                for (int nt = 0; nt < 8; ++nt) {
                    const int n = nt * 16 + l16;
                    float v = fmaxf((acc[mt][nt][r] - mn) * rs * sP[4 * l + 2][n] + sP[4 * l + 3][n], 0.f);
                    float h2 = hs_reg[mt][nt][r] + v;
                    hs_reg[mt][nt][r] = h2;
                    sHsT[n][i] = f2s(h2);
                }
            }
        __syncthreads();
    }

    float* sRedf = (float*)&sM[0][0];
    #pragma unroll
    for (int nt = 0; nt < 8; ++nt) {
        float part = 0.f;
        #pragma unroll
        for (int mt = 0; mt < 2; ++mt)
            #pragma unroll
            for (int r = 0; r < 4; ++r) part += hs_reg[mt][nt][r];
        sRedf[(wave * 4 + quad) * 128 + nt * 16 + l16] = part;
    }
    __syncthreads();
    if (t < 128) {
        float s = 0.f;
        #pragma unroll
        for (int r = 0; r < 16; ++r) s += sRedf[r * 128 + t];
        hsum[(size_t)b_s * 128 + t] = s;
    }
}

// ---------------- segment max over 16 subgraphs per graph ----------------
__global__ __launch_bounds__(128) void k_maxpool(const float* __restrict__ hs2, float* __restrict__ pooled)
{
    const int g = blockIdx.x, hd = threadIdx.x;
    float m = -INFINITY;
    for (int s = 0; s < 16; ++s) m = fmaxf(m, hs2[((size_t)(g * 16 + s)) * H_ + hd]);
    pooled[(size_t)g * H_ + hd] = m;
}

// ---------------- final projection ----------------
__global__ __launch_bounds__(128) void k_out(const float* __restrict__ pooled2,
    const float* __restrict__ out_W, const float* __restrict__ out_b, float* __restrict__ out)
{
    __shared__ float red[128];
    const int g = blockIdx.x, hd = threadIdx.x;
    red[hd] = pooled2[(size_t)g * H_ + hd] * out_W[hd];
    __syncthreads();
    for (int s = 64; s > 0; s >>= 1) {
        if (hd < s) red[hd] += red[hd + s];
        __syncthreads();
    }
    if (hd == 0) out[g] = red[0] + out_b[0];
}

extern "C" void kernel_launch(void* const* d_in, const int* in_sizes, int n_in,
                              void* d_out, int out_size, void* d_ws, size_t ws_size,
                              hipStream_t stream)
{
    (void)in_sizes; (void)n_in; (void)out_size; (void)ws_size;
    const float* x     = (const float*)d_in[0];
    const float* adj   = (const float*)d_in[1];
    const float* idemb = (const float*)d_in[2];
    const float* in_W1 = (const float*)d_in[3];
    const float* in_b1 = (const float*)d_in[4];
    const float* in_W2 = (const float*)d_in[5];
    const float* in_b2 = (const float*)d_in[6];
    const float* in_g  = (const float*)d_in[7];
    const float* in_bn = (const float*)d_in[8];
    const float* gW1   = (const float*)d_in[9];
    const float* gb1   = (const float*)d_in[10];
    const float* gW2   = (const float*)d_in[11];
    const float* gb2   = (const float*)d_in[12];
    const float* gg    = (const float*)d_in[13];
    const float* gbn   = (const float*)d_in[14];
    const float* iW1   = (const float*)d_in[15];
    const float* ib1   = (const float*)d_in[16];
    const float* iW2   = (const float*)d_in[17];
    const float* ib2   = (const float*)d_in[18];
    const float* ig    = (const float*)d_in[19];
    const float* ibn   = (const float*)d_in[20];
    const float* glW1  = (const float*)d_in[21];
    const float* glb1  = (const float*)d_in[22];
    const float* glW2  = (const float*)d_in[23];
    const float* glb2  = (const float*)d_in[24];
    const float* glg   = (const float*)d_in[25];
    const float* glbn  = (const float*)d_in[26];
    const float* s1_W  = (const float*)d_in[27];
    const float* s1_b  = (const float*)d_in[28];
    const float* s2_W  = (const float*)d_in[29];
    const float* s2_b  = (const float*)d_in[30];
    const float* rW1   = (const float*)d_in[31];
    const float* rb1   = (const float*)d_in[32];
    const float* rW2   = (const float*)d_in[33];
    const float* rb2   = (const float*)d_in[34];
    const float* rg    = (const float*)d_in[35];
    const float* rbn   = (const float*)d_in[36];
    const float* out_W = (const float*)d_in[37];
    const float* out_b = (const float*)d_in[38];
    const int* subgs   = (const int*)d_in[39];
    const int* num_node= (const int*)d_in[41];
    const int* allperm = (const int*)d_in[42];

    // ---- workspace layout (z2t eliminated; region A free except s1Wt) ----
    const size_t MB_ = (size_t)512 * 128 * P_ * H_ * 2;
    char* w = (char*)d_ws;
    bf16*  s1Wt   = (bf16*)(w + 33554432ull);                  // s1_W^T bf16 32KB
    bf16*  zm     = (bf16*)(w + MB_);                          // (512,128,128) bf16 = 16.8 MB
    bf16*  WT     = (bf16*)(w + MB_ + 16777216ull);            // 8 x (128x128) bf16 transposed
    char*  wc     = w + MB_ + 16777216ull + 262144ull;
    float* hb     = (float*)(wc);                              // h (32,128,128) f32  2 MB
    float* sb2    = (float*)(wc + 2097152ull);                 // t1 / g-layer msgs    2 MB
    bf16*  adjb   = (bf16*)(wc + 2097152ull);                  // reuse sb2 region after g-layers (1 MB)
    float* hsum   = (float*)(wc + 4194304ull);                 // (512,128)
    float* hs2    = (float*)(wc + 4456448ull);                 // (512,128)
    float* pooled = (float*)(wc + 4718592ull);                 // (32,128)
    float* pooled2= (float*)(wc + 4734976ull);                 // (32,128)
    unsigned char* nbr = (unsigned char*)(wc + 4751360ull);    // 4096*48 u8
    int*   deg    = (int*)(wc + 4947968ull);                   // 4096 i32
    float* degf   = (float*)(wc + 4964352ull);                 // 4096 f32
    float* outp   = (float*)d_out;

    // prep: CSR + transposed bf16 weights
    k_csr<<<32, 128, 0, stream>>>(adj, nbr, deg, degf);
    k_wt8<<<1024, 128, 0, stream>>>(iW1, iW2, iW1 + 16384, iW2 + 16384,
                                    glW1, glW2, glW1 + 16384, glW2 + 16384, WT);

    // input embedding block: h = block(x)
    k_in_t1<<<4096, 128, 0, stream>>>(x, in_W1, in_b1, sb2);
    k_block<false, false><<<256, 128, 0, stream>>>(sb2, nullptr, hb,
        nullptr, nullptr, in_W2, in_b2, in_g, in_bn);

    // graph message passing (3 layers) on h — small, keep VALU path
    for (int l = 0; l < 3; ++l) {
        k_spmv<<<4096, 128, 0, stream>>>(adj, hb, sb2, 0);
        k_block<true, true><<<256, 128, 0, stream>>>(sb2, hb, hb,
            gW1 + l * 16384, gb1 + l * 128, gW2 + l * 16384, gb2 + l * 128,
            gg + l * 128, gbn + l * 128);
    }

    // adjacency -> bf16 (sb2 region is dead now)
    k_adjb<<<4096, 128, 0, stream>>>(adj, adjb);

    // ID layers 1+2 fully fused -> zm (z2t never materialized)
    k_id12<<<512, 256, 0, stream>>>(adj, degf, adjb, num_node, subgs, allperm, idemb, zm,
        WT, ib1, ib2, ig, ibn);

    // s1_W^T
    k_wt1<<<128, 128, 0, stream>>>(s1_W, s1Wt);

    // fused: setmlp1 + 2 gl layers + node-sum -> hsum
    k_gl_fused<<<512, 256, 0, stream>>>(zm, hb, adjb, s1Wt, s1_b,
        WT + 4 * 16384, glb1, glb2, glg, glbn, hsum);

    // setmlp2 -> segment max -> setmlp3 block -> output proj
    k_gemm_relu<false, float><<<32, 128, 0, stream>>>(hsum, nullptr, hs2, s2_W, s2_b);
    k_maxpool<<<32, 128, 0, stream>>>(hs2, pooled);
    k_block<true, true><<<2, 128, 0, stream>>>(pooled, pooled, pooled2,
        rW1, rb1, rW2, rb2, rg, rbn);
    k_out<<<32, 128, 0, stream>>>(pooled2, out_W, out_b, outp);
}

// Round 15
// 730.868 us; speedup vs baseline: 1.3117x; 1.3117x over previous
//
#include <hip/hip_runtime.h>
#include <hip/hip_bf16.h>
#include <string.h>

typedef __hip_bfloat16 bf16;
typedef short v8s __attribute__((ext_vector_type(8)));
typedef float v4f __attribute__((ext_vector_type(4)));

#define H_ 128
#define P_ 6
#define K_ 4
#define NBR_CAP 48

__device__ __forceinline__ float ldf(const float* p, size_t i) { return p[i]; }
__device__ __forceinline__ float ldf(const bf16* p, size_t i) { return __bfloat162float(p[i]); }

__device__ __forceinline__ float s2f(short s) {
    unsigned int u = ((unsigned int)(unsigned short)s) << 16;
    float f; __builtin_memcpy(&f, &u, 4); return f;
}
__device__ __forceinline__ short f2s(float v) {
    bf16 h = __float2bfloat16(v);
    short s; __builtin_memcpy(&s, &h, 2); return s;
}
__device__ __forceinline__ v4f MFMA(v8s a, v8s b, v4f c) {
    return __builtin_amdgcn_mfma_f32_16x16x32_bf16(a, b, c, 0, 0, 0);
}

// ---------------- CSR build: neighbor u8 lists + degree + float rowsum ----------------
__global__ __launch_bounds__(128) void k_csr(const float* __restrict__ adj,
    unsigned char* __restrict__ nbr, int* __restrict__ deg, float* __restrict__ degf)
{
    const int gi = blockIdx.x * 128 + threadIdx.x;   // (g,i), 4096 rows
    const float* row = adj + (size_t)gi * 128;
    unsigned char* nb = nbr + (size_t)gi * NBR_CAP;
    int c = 0; float s = 0.f;
    for (int j = 0; j < 128; ++j) {
        float a = row[j];
        if (a != 0.f) { s += a; if (c < NBR_CAP) nb[c] = (unsigned char)j; ++c; }
    }
    deg[gi] = (c < NBR_CAP) ? c : NBR_CAP;
    degf[gi] = s;
}

// ---------------- adjacency -> bf16 (values are exactly 0/1) ----------------
__global__ __launch_bounds__(128) void k_adjb(const float* __restrict__ adj, bf16* __restrict__ adjb)
{
    const size_t i = (size_t)blockIdx.x * 128 + threadIdx.x;
    adjb[i] = __float2bfloat16(adj[i]);
}

// ---------------- transpose 8 (128x128) weights to bf16 WT[n][k] ----------------
__global__ __launch_bounds__(128) void k_wt8(
    const float* s0, const float* s1, const float* s2, const float* s3,
    const float* s4, const float* s5, const float* s6, const float* s7,
    bf16* __restrict__ dst)
{
    const int w = blockIdx.x >> 7, n = blockIdx.x & 127, k = threadIdx.x;
    const float* arr[8] = {s0, s1, s2, s3, s4, s5, s6, s7};
    dst[(size_t)w * 16384 + n * 128 + k] = __float2bfloat16(arr[w][k * 128 + n]);
}

// ---------------- transpose single 128x128 weight to bf16 ----------------
__global__ __launch_bounds__(128) void k_wt1(const float* __restrict__ src, bf16* __restrict__ dst)
{
    const int n = blockIdx.x, k = threadIdx.x;
    dst[n * 128 + k] = __float2bfloat16(src[k * 128 + n]);
}

// ---------------- input embedding: t1 = relu(x * W1 + b1) ----------------
__global__ __launch_bounds__(128) void k_in_t1(const float* __restrict__ x,
    const float* __restrict__ W1, const float* __restrict__ b1, float* __restrict__ t1)
{
    int r = blockIdx.x, hd = threadIdx.x;
    t1[(size_t)r * H_ + hd] = fmaxf(fmaf(x[r], W1[hd], b1[hd]), 0.f);
}

// ---------------- generic VALU fused block (used for small row counts) ----------------
template<bool DO_MM1, bool HAS_RES>
__global__ __launch_bounds__(128) void k_block(
    const float* __restrict__ in, const float* __restrict__ res, float* __restrict__ out,
    const float* __restrict__ W1, const float* __restrict__ b1,
    const float* __restrict__ W2, const float* __restrict__ b2,
    const float* __restrict__ gam, const float* __restrict__ bet)
{
    __shared__ float sA[16][136];
    __shared__ float sB[16][136];
    __shared__ float sStat[32];
    const int hd = threadIdx.x;
    const size_t row0 = (size_t)blockIdx.x * 16;
    #pragma unroll
    for (int r = 0; r < 16; ++r) sA[r][hd] = in[(row0 + r) * H_ + hd];
    __syncthreads();
    float acc[16];
    if (DO_MM1) {
        #pragma unroll
        for (int r = 0; r < 16; ++r) acc[r] = b1[hd];
        for (int k = 0; k < H_; k += 4) {
            float w0 = W1[(k+0)*H_+hd], w1 = W1[(k+1)*H_+hd], w2 = W1[(k+2)*H_+hd], w3 = W1[(k+3)*H_+hd];
            #pragma unroll
            for (int r = 0; r < 16; ++r) {
                float4 a = *(const float4*)&sA[r][k];
                acc[r] = fmaf(a.x, w0, acc[r]); acc[r] = fmaf(a.y, w1, acc[r]);
                acc[r] = fmaf(a.z, w2, acc[r]); acc[r] = fmaf(a.w, w3, acc[r]);
            }
        }
        #pragma unroll
        for (int r = 0; r < 16; ++r) sB[r][hd] = fmaxf(acc[r], 0.f);
    } else {
        #pragma unroll
        for (int r = 0; r < 16; ++r) sB[r][hd] = sA[r][hd];
    }
    __syncthreads();
    #pragma unroll
    for (int r = 0; r < 16; ++r) acc[r] = b2[hd];
    for (int k = 0; k < H_; k += 4) {
        float w0 = W2[(k+0)*H_+hd], w1 = W2[(k+1)*H_+hd], w2 = W2[(k+2)*H_+hd], w3 = W2[(k+3)*H_+hd];
        #pragma unroll
        for (int r = 0; r < 16; ++r) {
            float4 a = *(const float4*)&sB[r][k];
            acc[r] = fmaf(a.x, w0, acc[r]); acc[r] = fmaf(a.y, w1, acc[r]);
            acc[r] = fmaf(a.z, w2, acc[r]); acc[r] = fmaf(a.w, w3, acc[r]);
        }
    }
    __syncthreads();
    #pragma unroll
    for (int r = 0; r < 16; ++r) sA[r][hd] = acc[r];
    __syncthreads();
    if (hd < 16) {
        float s = 0.f, ss = 0.f;
        for (int k = 0; k < H_; ++k) { float v = sA[hd][k]; s += v; ss += v * v; }
        float mean = s * (1.f / H_);
        float var = ss * (1.f / H_) - mean * mean;
        sStat[hd] = mean; sStat[16 + hd] = rsqrtf(var + 1e-5f);
    }
    __syncthreads();
    float gv = gam[hd], bv = bet[hd];
    #pragma unroll
    for (int r = 0; r < 16; ++r) {
        float v = fmaxf((acc[r] - sStat[r]) * sStat[16 + r] * gv + bv, 0.f);
        if (HAS_RES) v += res[(row0 + r) * H_ + hd];
        out[(row0 + r) * H_ + hd] = v;
    }
}

// ---------------- gemm + bias + relu ----------------
template<bool GATHER, typename T>
__global__ __launch_bounds__(128) void k_gemm_relu(
    const T* __restrict__ in, const float* __restrict__ res, float* __restrict__ out,
    const float* __restrict__ W, const float* __restrict__ b)
{
    __shared__ float sA[16][136];
    const int hd = threadIdx.x;
    const size_t row0 = (size_t)blockIdx.x * 16;
    #pragma unroll
    for (int r = 0; r < 16; ++r) sA[r][hd] = ldf(in, (row0 + r) * H_ + hd);
    __syncthreads();
    float acc[16];
    #pragma unroll
    for (int r = 0; r < 16; ++r) acc[r] = b[hd];
    for (int k = 0; k < H_; k += 4) {
        float w0 = W[(k+0)*H_+hd], w1 = W[(k+1)*H_+hd], w2 = W[(k+2)*H_+hd], w3 = W[(k+3)*H_+hd];
        #pragma unroll
        for (int r = 0; r < 16; ++r) {
            float4 a = *(const float4*)&sA[r][k];
            acc[r] = fmaf(a.x, w0, acc[r]); acc[r] = fmaf(a.y, w1, acc[r]);
            acc[r] = fmaf(a.z, w2, acc[r]); acc[r] = fmaf(a.w, w3, acc[r]);
        }
    }
    #pragma unroll
    for (int r = 0; r < 16; ++r) {
        size_t rr = row0 + r;
        float v = fmaxf(acc[r], 0.f);
        if (GATHER) {
            int i = (int)(rr & 127);
            int g = (int)(rr >> 11);
            v += res[((size_t)(g * 128 + i)) * H_ + hd];
        }
        out[rr * H_ + hd] = v;
    }
}

// ---------------- dense sparse-matvec for g-layers (small, keep VALU) ----------------
__global__ __launch_bounds__(128) void k_spmv(const float* __restrict__ adj,
    const float* __restrict__ xin, float* __restrict__ mout, int subShift)
{
    __shared__ float sAdj[128];
    const int hd = threadIdx.x;
    const int bi = blockIdx.x;
    const int bb = bi >> 7, i = bi & 127;
    const int g = bb >> subShift;
    sAdj[hd] = adj[((size_t)(g * 128 + i)) * 128 + hd];
    __syncthreads();
    float acc = 0.f;
    const float* xb = xin + (size_t)bb * 128 * H_ + hd;
    for (int j = 0; j < 128; ++j) {
        float a = sAdj[j];
        if (a != 0.f) acc = fmaf(a, xb[(size_t)j * H_], acc);
    }
    mout[(size_t)bi * H_ + hd] = acc;
}

// ---------------- ID layer 1 FUSED v2: single LDS buffer (m/T1/z aliased, v9 discipline)
// LDS 71.7 -> 36.9 KB => 2+ blocks/CU (was 1; Occ 21.7%, MfmaUtil 6.5% at 155 us).
// m computed in-LDS (closed form) -> MFMA MLP -> z2t transposed slices. VGPR ~92.
__global__ __launch_bounds__(256) void k_id1_fused(
    const float* __restrict__ adj, const float* __restrict__ degf,
    const int* __restrict__ subgs, const int* __restrict__ allperm,
    const float* __restrict__ idemb, bf16* __restrict__ outb,
    const bf16* __restrict__ W1t, const float* __restrict__ b1,
    const bf16* __restrict__ W2t, const float* __restrict__ b2,
    const float* __restrict__ gam, const float* __restrict__ bet)
{
    __shared__ __align__(16) short sB[128][136];    // m -> T1 -> z  (aliased)  34.8 KB
    __shared__ float sE[K_][128];                   // idemb rows - 1            2.0 KB
    const int t = threadIdx.x;
    const int bi = blockIdx.x;          // 3072 = 512 * 6
    const int b_s = bi / 6, p = bi - b_s * 6;
    const int g = b_s >> 4;
    const int wave = t >> 6, lane = t & 63;
    const int quad = lane >> 4, l16 = lane & 15;
    const int wrow = wave << 5;

    int nodeq[K_];
    #pragma unroll
    for (int q = 0; q < K_; ++q) nodeq[q] = subgs[b_s * K_ + q];

    for (int u = t; u < K_ * 128; u += 256) {
        const int q = u >> 7, f = u & 127;
        sE[q][f] = idemb[(size_t)allperm[q * P_ + p] * H_ + f] - 1.f;
    }
    __syncthreads();

    // compute m rows into sB: thread t -> row i = t>>1, cols [half, half+64)
    {
        const int i = t >> 1, half = (t & 1) * 64;
        const int gi = g * 128 + i;
        const float dg = degf[gi];
        float aq[K_];
        #pragma unroll
        for (int q = 0; q < K_; ++q) aq[q] = adj[(size_t)gi * 128 + nodeq[q]];
        #pragma unroll
        for (int f = 0; f < 64; ++f) {
            float v = dg;
            #pragma unroll
            for (int q = 0; q < K_; ++q) v = fmaf(aq[q], sE[q][half + f], v);
            sB[i][half + f] = f2s(v);
        }
    }
    __syncthreads();

    // MM1: T1 = relu(m @ W1 + b1)  (wave-own rows: read then overwrite in-place)
    v4f acc[2][8];
    #pragma unroll
    for (int mt = 0; mt < 2; ++mt)
        #pragma unroll
        for (int nt = 0; nt < 8; ++nt) acc[mt][nt] = (v4f){0.f, 0.f, 0.f, 0.f};
    #pragma unroll
    for (int kk = 0; kk < 4; ++kk) {
        v8s a0 = *(const v8s*)&sB[wrow + l16][kk * 32 + quad * 8];
        v8s a1 = *(const v8s*)&sB[wrow + 16 + l16][kk * 32 + quad * 8];
        #pragma unroll
        for (int nt = 0; nt < 8; ++nt) {
            v8s b = *(const v8s*)(W1t + (nt * 16 + l16) * 128 + kk * 32 + quad * 8);
            acc[0][nt] = MFMA(a0, b, acc[0][nt]);
            acc[1][nt] = MFMA(a1, b, acc[1][nt]);
        }
    }
    #pragma unroll
    for (int nt = 0; nt < 8; ++nt) {
        float bb = b1[nt * 16 + l16];
        #pragma unroll
        for (int mt = 0; mt < 2; ++mt)
            #pragma unroll
            for (int r = 0; r < 4; ++r)
                sB[wrow + mt * 16 + quad * 4 + r][nt * 16 + l16] = f2s(fmaxf(acc[mt][nt][r] + bb, 0.f));
    }
    // MM2: u = T1 @ W2 + b2
    #pragma unroll
    for (int mt = 0; mt < 2; ++mt)
        #pragma unroll
        for (int nt = 0; nt < 8; ++nt) acc[mt][nt] = (v4f){0.f, 0.f, 0.f, 0.f};
    #pragma unroll
    for (int kk = 0; kk < 4; ++kk) {
        v8s a0 = *(const v8s*)&sB[wrow + l16][kk * 32 + quad * 8];
        v8s a1 = *(const v8s*)&sB[wrow + 16 + l16][kk * 32 + quad * 8];
        #pragma unroll
        for (int nt = 0; nt < 8; ++nt) {
            v8s b = *(const v8s*)(W2t + (nt * 16 + l16) * 128 + kk * 32 + quad * 8);
            acc[0][nt] = MFMA(a0, b, acc[0][nt]);
            acc[1][nt] = MFMA(a1, b, acc[1][nt]);
        }
    }
    // epilogue: bias, LN (per row), relu, +1 residual -> z into sB wave-own rows
    float bb2[8], gv[8], bv[8];
    #pragma unroll
    for (int nt = 0; nt < 8; ++nt) {
        int n = nt * 16 + l16;
        bb2[nt] = b2[n]; gv[nt] = gam[n]; bv[nt] = bet[n];
    }
    #pragma unroll
    for (int mt = 0; mt < 2; ++mt)
        #pragma unroll
        for (int r = 0; r < 4; ++r) {
            float s = 0.f, q = 0.f;
            #pragma unroll
            for (int nt = 0; nt < 8; ++nt) {
                float u = acc[mt][nt][r] + bb2[nt];
                acc[mt][nt][r] = u;
                s += u; q += u * u;
            }
            #pragma unroll
            for (int d = 1; d < 16; d <<= 1) {
                s += __shfl_xor(s, d);
                q += __shfl_xor(q, d);
            }
            float mn = s * (1.f / 128.f);
            float rs = rsqrtf(q * (1.f / 128.f) - mn * mn + 1e-5f);
            #pragma unroll
            for (int nt = 0; nt < 8; ++nt) {
                float v = fmaxf((acc[mt][nt][r] - mn) * rs * gv[nt] + bv[nt], 0.f);
                sB[wrow + mt * 16 + quad * 4 + r][nt * 16 + l16] = f2s(v + 1.0f);
            }
        }
    __syncthreads();
    // transposed store: [f][node]
    {
        const int f = t >> 1, nh = (t & 1) * 64;
        const short* flat = &sB[0][0];             // [128 node][136]
        bf16* dst = outb + (size_t)bi * 16384 + (size_t)f * 128 + nh;
        #pragma unroll
        for (int u = 0; u < 8; ++u) {
            v8s pk;
            #pragma unroll
            for (int e = 0; e < 8; ++e) pk[e] = flat[(nh + u * 8 + e) * 136 + f];
            *(v8s*)(dst + u * 8) = pk;
        }
    }
}

// ---------------- ID layer 2 v9: single shared buffer (passing, R13) ----------------
__global__ __launch_bounds__(256) void k_id2_v9(
    const bf16* __restrict__ z2t, bf16* __restrict__ zm,
    const bf16* __restrict__ adjb, const int* __restrict__ num_node,
    const int* __restrict__ subgs, const int* __restrict__ allperm,
    const float* __restrict__ idemb,
    const bf16* __restrict__ W1t, const float* __restrict__ b1,
    const bf16* __restrict__ W2t, const float* __restrict__ b2,
    const float* __restrict__ gam, const float* __restrict__ bet)
{
    __shared__ __align__(16) short sB[128][136];   // Zp [f][node], then M/T [node][f]  34.8 KB
    __shared__ float sP[4][128];                   // b1, b2, gam, bet                   2.0 KB
    const int t = threadIdx.x;
    const int b_s = blockIdx.x;
    const int g = b_s >> 4;
    const int wave = t >> 6, lane = t & 63, quad = lane >> 4, l16 = lane & 15;
    const int wrow = wave << 5;

    #pragma unroll
    for (int u = 0; u < 2; ++u) {
        const int v = t + u * 256;
        const int a = v >> 7, n = v & 127;
        const float* src = (a == 0) ? b1 : (a == 1) ? b2 : (a == 2) ? gam : bet;
        sP[a][n] = src[n];
    }

    v8s aA[2][4];
    {
        const bf16* ar = adjb + (size_t)g * 16384;
        #pragma unroll
        for (int mt = 0; mt < 2; ++mt)
            #pragma unroll
            for (int kk = 0; kk < 4; ++kk)
                aA[mt][kk] = *(const v8s*)(ar + (size_t)(wrow + mt * 16 + l16) * 128 + kk * 32 + quad * 8);
    }
    int nodeq[K_];
    #pragma unroll
    for (int q = 0; q < K_; ++q) nodeq[q] = subgs[b_s * K_ + q];

    float macc[2][8][4];
    #pragma unroll
    for (int mt = 0; mt < 2; ++mt)
        #pragma unroll
        for (int nt = 0; nt < 8; ++nt)
            #pragma unroll
            for (int r = 0; r < 4; ++r) macc[mt][nt][r] = 0.f;

    const int sf = t >> 1, shalf = (t & 1) * 64;

    for (int p = 0; p < P_; ++p) {
        {
            const bf16* src = z2t + ((size_t)(b_s * P_ + p)) * 16384 + (size_t)sf * 128 + shalf;
            #pragma unroll
            for (int u = 0; u < 8; ++u)
                *(v8s*)&sB[sf][shalf + u * 8] = *(const v8s*)(src + u * 8);
        }
        __syncthreads();
        if (t < 128) {
            #pragma unroll
            for (int q = 0; q < K_; ++q) {
                float e = idemb[(size_t)allperm[q * P_ + p] * H_ + t] - 1.f;
                short* cell = &sB[t][nodeq[q]];
                *cell = f2s(s2f(*cell) + e);
            }
        }
        __syncthreads();
        #pragma unroll
        for (int mt = 0; mt < 2; ++mt)
            #pragma unroll
            for (int nt = 0; nt < 8; ++nt) {
                const int n = nt * 16 + l16;
                #pragma unroll
                for (int r = 0; r < 4; ++r)
                    macc[mt][nt][r] += s2f(sB[n][wrow + mt * 16 + quad * 4 + r]);
            }
        v4f acc[2][8];
        #pragma unroll
        for (int mt = 0; mt < 2; ++mt)
            #pragma unroll
            for (int nt = 0; nt < 8; ++nt) acc[mt][nt] = (v4f){0.f, 0.f, 0.f, 0.f};
        #pragma unroll
        for (int kk = 0; kk < 4; ++kk)
            #pragma unroll
            for (int nt = 0; nt < 8; ++nt) {
                v8s b = *(const v8s*)&sB[nt * 16 + l16][kk * 32 + quad * 8];
                acc[0][nt] = MFMA(aA[0][kk], b, acc[0][nt]);
                acc[1][nt] = MFMA(aA[1][kk], b, acc[1][nt]);
            }
        __syncthreads();
        #pragma unroll
        for (int nt = 0; nt < 8; ++nt)
            #pragma unroll
            for (int mt = 0; mt < 2; ++mt)
                #pragma unroll
                for (int r = 0; r < 4; ++r)
                    sB[wrow + mt * 16 + quad * 4 + r][nt * 16 + l16] = f2s(acc[mt][nt][r]);
        #pragma unroll
        for (int mt = 0; mt < 2; ++mt)
            #pragma unroll
            for (int nt = 0; nt < 8; ++nt) acc[mt][nt] = (v4f){0.f, 0.f, 0.f, 0.f};
        #pragma unroll
        for (int kk = 0; kk < 4; ++kk) {
            v8s a0 = *(const v8s*)&sB[wrow + l16][kk * 32 + quad * 8];
            v8s a1 = *(const v8s*)&sB[wrow + 16 + l16][kk * 32 + quad * 8];
            #pragma unroll
            for (int nt = 0; nt < 8; ++nt) {
                v8s b = *(const v8s*)(W1t + (nt * 16 + l16) * 128 + kk * 32 + quad * 8);
                acc[0][nt] = MFMA(a0, b, acc[0][nt]);
                acc[1][nt] = MFMA(a1, b, acc[1][nt]);
            }
        }
        #pragma unroll
        for (int nt = 0; nt < 8; ++nt) {
            float bb = sP[0][nt * 16 + l16];
            #pragma unroll
            for (int mt = 0; mt < 2; ++mt)
                #pragma unroll
                for (int r = 0; r < 4; ++r)
                    sB[wrow + mt * 16 + quad * 4 + r][nt * 16 + l16] = f2s(fmaxf(acc[mt][nt][r] + bb, 0.f));
        }
        #pragma unroll
        for (int mt = 0; mt < 2; ++mt)
            #pragma unroll
            for (int nt = 0; nt < 8; ++nt) acc[mt][nt] = (v4f){0.f, 0.f, 0.f, 0.f};
        #pragma unroll
        for (int kk = 0; kk < 4; ++kk) {
            v8s a0 = *(const v8s*)&sB[wrow + l16][kk * 32 + quad * 8];
            v8s a1 = *(const v8s*)&sB[wrow + 16 + l16][kk * 32 + quad * 8];
            #pragma unroll
            for (int nt = 0; nt < 8; ++nt) {
                v8s b = *(const v8s*)(W2t + (nt * 16 + l16) * 128 + kk * 32 + quad * 8);
                acc[0][nt] = MFMA(a0, b, acc[0][nt]);
                acc[1][nt] = MFMA(a1, b, acc[1][nt]);
            }
        }
        #pragma unroll
        for (int mt = 0; mt < 2; ++mt)
            #pragma unroll
            for (int r = 0; r < 4; ++r) {
                float s = 0.f, qq = 0.f;
                #pragma unroll
                for (int nt = 0; nt < 8; ++nt) {
                    float u = acc[mt][nt][r] + sP[1][nt * 16 + l16];
                    acc[mt][nt][r] = u;
                    s += u; qq += u * u;
                }
                #pragma unroll
                for (int d = 1; d < 16; d <<= 1) {
                    s += __shfl_xor(s, d);
                    qq += __shfl_xor(qq, d);
                }
                float mn = s * (1.f / 128.f);
                float rs = rsqrtf(qq * (1.f / 128.f) - mn * mn + 1e-5f);
                #pragma unroll
                for (int nt = 0; nt < 8; ++nt) {
                    const int n = nt * 16 + l16;
                    macc[mt][nt][r] += fmaxf((acc[mt][nt][r] - mn) * rs * sP[2][n] + sP[3][n], 0.f);
                }
            }
        __syncthreads();
    }
    const int nn = num_node[g];
    #pragma unroll
    for (int mt = 0; mt < 2; ++mt)
        #pragma unroll
        for (int nt = 0; nt < 8; ++nt)
            #pragma unroll
            for (int r = 0; r < 4; ++r) {
                const int i = wrow + mt * 16 + quad * 4 + r;
                const int n = nt * 16 + l16;
                float v = (i >= nn) ? 0.f : macc[mt][nt][r] * (1.f / 6.f);
                zm[((size_t)(b_s * 128 + i)) * 128 + n] = __float2bfloat16(v);
            }
}

// ---------------- fused gl stage: setmlp1 + 2 gl layers + node-sum (passing, R11) ----------------
__global__ __launch_bounds__(256) void k_gl_fused(
    const bf16* __restrict__ zm, const float* __restrict__ hb,
    const bf16* __restrict__ adjb,
    const bf16* __restrict__ s1Wt, const float* __restrict__ s1_b,
    const bf16* __restrict__ WTgl,          // glW1t[0], glW2t[0], glW1t[1], glW2t[1]
    const float* __restrict__ glb1, const float* __restrict__ glb2,
    const float* __restrict__ glg, const float* __restrict__ glbn,
    float* __restrict__ hsum)
{
    __shared__ __align__(16) short sHsT[128][136];  // Hs^T bf16 [f][node]  34.8 KB
    __shared__ __align__(16) short sM[128][136];    // M / T scratch        34.8 KB (reused as f32 sRed)
    __shared__ float sP[9][128];                    // gl biases x2 + s1_b   4.5 KB
    const int t = threadIdx.x;
    const int b_s = blockIdx.x;
    const int g = b_s >> 4;
    const int wave = t >> 6, lane = t & 63, quad = lane >> 4, l16 = lane & 15;
    const int wrow = wave << 5;

    for (int u = t; u < 9 * 128; u += 256) {
        const int a = u >> 7, n = u & 127;
        const float* src =
            (a == 0) ? glb1 : (a == 1) ? glb2 : (a == 2) ? glg : (a == 3) ? glbn :
            (a == 4) ? glb1 + 128 : (a == 5) ? glb2 + 128 : (a == 6) ? glg + 128 :
            (a == 7) ? glbn + 128 : s1_b;
        sP[a][n] = src[n];
    }

    v8s aA[2][4];
    {
        const bf16* ar = adjb + (size_t)g * 16384;
        #pragma unroll
        for (int mt = 0; mt < 2; ++mt)
            #pragma unroll
            for (int kk = 0; kk < 4; ++kk)
                aA[mt][kk] = *(const v8s*)(ar + (size_t)(wrow + mt * 16 + l16) * 128 + kk * 32 + quad * 8);
    }

    // ---- setmlp1: hs = relu(zm @ s1W + s1b) + h[g] ----
    v4f acc[2][8];
    #pragma unroll
    for (int mt = 0; mt < 2; ++mt)
        #pragma unroll
        for (int nt = 0; nt < 8; ++nt) acc[mt][nt] = (v4f){0.f, 0.f, 0.f, 0.f};
    #pragma unroll
    for (int kk = 0; kk < 4; ++kk) {
        v8s a0 = *(const v8s*)(zm + ((size_t)(b_s * 128) + wrow + l16) * 128 + kk * 32 + quad * 8);
        v8s a1 = *(const v8s*)(zm + ((size_t)(b_s * 128) + wrow + 16 + l16) * 128 + kk * 32 + quad * 8);
        #pragma unroll
        for (int nt = 0; nt < 8; ++nt) {
            v8s b = *(const v8s*)(s1Wt + (nt * 16 + l16) * 128 + kk * 32 + quad * 8);
            acc[0][nt] = MFMA(a0, b, acc[0][nt]);
            acc[1][nt] = MFMA(a1, b, acc[1][nt]);
        }
    }
    __syncthreads();
    float hs_reg[2][8][4];
    #pragma unroll
    for (int mt = 0; mt < 2; ++mt)
        #pragma unroll
        for (int nt = 0; nt < 8; ++nt)
            #pragma unroll
            for (int r = 0; r < 4; ++r) {
                const int i = wrow + mt * 16 + quad * 4 + r;
                const int n = nt * 16 + l16;
                float v = fmaxf(acc[mt][nt][r] + sP[8][n], 0.f);
                v += hb[((size_t)(g * 128 + i)) * 128 + n];
                hs_reg[mt][nt][r] = v;
                sHsT[n][i] = f2s(v);
            }
    __syncthreads();

    for (int l = 0; l < 2; ++l) {
        const bf16* W1t = WTgl + (size_t)(2 * l) * 16384;
        const bf16* W2t = WTgl + (size_t)(2 * l + 1) * 16384;
        #pragma unroll
        for (int mt = 0; mt < 2; ++mt)
            #pragma unroll
            for (int nt = 0; nt < 8; ++nt) acc[mt][nt] = (v4f){0.f, 0.f, 0.f, 0.f};
        #pragma unroll
        for (int kk = 0; kk < 4; ++kk)
            #pragma unroll
            for (int nt = 0; nt < 8; ++nt) {
                v8s b = *(const v8s*)&sHsT[nt * 16 + l16][kk * 32 + quad * 8];
                acc[0][nt] = MFMA(aA[0][kk], b, acc[0][nt]);
                acc[1][nt] = MFMA(aA[1][kk], b, acc[1][nt]);
            }
        #pragma unroll
        for (int nt = 0; nt < 8; ++nt)
            #pragma unroll
            for (int mt = 0; mt < 2; ++mt)
                #pragma unroll
                for (int r = 0; r < 4; ++r)
                    sM[wrow + mt * 16 + quad * 4 + r][nt * 16 + l16] = f2s(acc[mt][nt][r]);
        __syncthreads();
        #pragma unroll
        for (int mt = 0; mt < 2; ++mt)
            #pragma unroll
            for (int nt = 0; nt < 8; ++nt) acc[mt][nt] = (v4f){0.f, 0.f, 0.f, 0.f};
        #pragma unroll
        for (int kk = 0; kk < 4; ++kk) {
            v8s a0 = *(const v8s*)&sM[wrow + l16][kk * 32 + quad * 8];
            v8s a1 = *(const v8s*)&sM[wrow + 16 + l16][kk * 32 + quad * 8];
            #pragma unroll
            for (int nt = 0; nt < 8; ++nt) {
                v8s b = *(const v8s*)(W1t + (nt * 16 + l16) * 128 + kk * 32 + quad * 8);
                acc[0][nt] = MFMA(a0, b, acc[0][nt]);
                acc[1][nt] = MFMA(a1, b, acc[1][nt]);
            }
        }
        #pragma unroll
        for (int nt = 0; nt < 8; ++nt) {
            float bb = sP[4 * l + 0][nt * 16 + l16];
            #pragma unroll
            for (int mt = 0; mt < 2; ++mt)
                #pragma unroll
                for (int r = 0; r < 4; ++r)
                    sM[wrow + mt * 16 + quad * 4 + r][nt * 16 + l16] = f2s(fmaxf(acc[mt][nt][r] + bb, 0.f));
        }
        #pragma unroll
        for (int mt = 0; mt < 2; ++mt)
            #pragma unroll
            for (int nt = 0; nt < 8; ++nt) acc[mt][nt] = (v4f){0.f, 0.f, 0.f, 0.f};
        #pragma unroll
        for (int kk = 0; kk < 4; ++kk) {
            v8s a0 = *(const v8s*)&sM[wrow + l16][kk * 32 + quad * 8];
            v8s a1 = *(const v8s*)&sM[wrow + 16 + l16][kk * 32 + quad * 8];
            #pragma unroll
            for (int nt = 0; nt < 8; ++nt) {
                v8s b = *(const v8s*)(W2t + (nt * 16 + l16) * 128 + kk * 32 + quad * 8);
                acc[0][nt] = MFMA(a0, b, acc[0][nt]);
                acc[1][nt] = MFMA(a1, b, acc[1][nt]);
            }
        }
        #pragma unroll
        for (int mt = 0; mt < 2; ++mt)
            #pragma unroll
            for (int r = 0; r < 4; ++r) {
                float s = 0.f, qq = 0.f;
                #pragma unroll
                for (int nt = 0; nt < 8; ++nt) {
                    float u = acc[mt][nt][r] + sP[4 * l + 1][nt * 16 + l16];
                    acc[mt][nt][r] = u;
                    s += u; qq += u * u;
                }
                #pragma unroll
                for (int d = 1; d < 16; d <<= 1) {
                    s += __shfl_xor(s, d);
                    qq += __shfl_xor(qq, d);
                }
                float mn = s * (1.f / 128.f);
                float rs = rsqrtf(qq * (1.f / 128.f) - mn * mn + 1e-5f);
                const int i = wrow + mt * 16 + quad * 4 + r;
                #pragma unroll
                for (int nt = 0; nt < 8; ++nt) {
                    const int n = nt * 16 + l16;
                    float v = fmaxf((acc[mt][nt][r] - mn) * rs * sP[4 * l + 2][n] + sP[4 * l + 3][n], 0.f);
                    float h2 = hs_reg[mt][nt][r] + v;
                    hs_reg[mt][nt][r] = h2;
                    sHsT[n][i] = f2s(h2);
                }
            }
        __syncthreads();
    }

    float* sRedf = (float*)&sM[0][0];
    #pragma unroll
    for (int nt = 0; nt < 8; ++nt) {
        float part = 0.f;
        #pragma unroll
        for (int mt = 0; mt < 2; ++mt)
            #pragma unroll
            for (int r = 0; r < 4; ++r) part += hs_reg[mt][nt][r];
        sRedf[(wave * 4 + quad) * 128 + nt * 16 + l16] = part;
    }
    __syncthreads();
    if (t < 128) {
        float s = 0.f;
        #pragma unroll
        for (int r = 0; r < 16; ++r) s += sRedf[r * 128 + t];
        hsum[(size_t)b_s * 128 + t] = s;
    }
}

// ---------------- segment max over 16 subgraphs per graph ----------------
__global__ __launch_bounds__(128) void k_maxpool(const float* __restrict__ hs2, float* __restrict__ pooled)
{
    const int g = blockIdx.x, hd = threadIdx.x;
    float m = -INFINITY;
    for (int s = 0; s < 16; ++s) m = fmaxf(m, hs2[((size_t)(g * 16 + s)) * H_ + hd]);
    pooled[(size_t)g * H_ + hd] = m;
}

// ---------------- final projection ----------------
__global__ __launch_bounds__(128) void k_out(const float* __restrict__ pooled2,
    const float* __restrict__ out_W, const float* __restrict__ out_b, float* __restrict__ out)
{
    __shared__ float red[128];
    const int g = blockIdx.x, hd = threadIdx.x;
    red[hd] = pooled2[(size_t)g * H_ + hd] * out_W[hd];
    __syncthreads();
    for (int s = 64; s > 0; s >>= 1) {
        if (hd < s) red[hd] += red[hd + s];
        __syncthreads();
    }
    if (hd == 0) out[g] = red[0] + out_b[0];
}

extern "C" void kernel_launch(void* const* d_in, const int* in_sizes, int n_in,
                              void* d_out, int out_size, void* d_ws, size_t ws_size,
                              hipStream_t stream)
{
    (void)in_sizes; (void)n_in; (void)out_size; (void)ws_size;
    const float* x     = (const float*)d_in[0];
    const float* adj   = (const float*)d_in[1];
    const float* idemb = (const float*)d_in[2];
    const float* in_W1 = (const float*)d_in[3];
    const float* in_b1 = (const float*)d_in[4];
    const float* in_W2 = (const float*)d_in[5];
    const float* in_b2 = (const float*)d_in[6];
    const float* in_g  = (const float*)d_in[7];
    const float* in_bn = (const float*)d_in[8];
    const float* gW1   = (const float*)d_in[9];
    const float* gb1   = (const float*)d_in[10];
    const float* gW2   = (const float*)d_in[11];
    const float* gb2   = (const float*)d_in[12];
    const float* gg    = (const float*)d_in[13];
    const float* gbn   = (const float*)d_in[14];
    const float* iW1   = (const float*)d_in[15];
    const float* ib1   = (const float*)d_in[16];
    const float* iW2   = (const float*)d_in[17];
    const float* ib2   = (const float*)d_in[18];
    const float* ig    = (const float*)d_in[19];
    const float* ibn   = (const float*)d_in[20];
    const float* glW1  = (const float*)d_in[21];
    const float* glb1  = (const float*)d_in[22];
    const float* glW2  = (const float*)d_in[23];
    const float* glb2  = (const float*)d_in[24];
    const float* glg   = (const float*)d_in[25];
    const float* glbn  = (const float*)d_in[26];
    const float* s1_W  = (const float*)d_in[27];
    const float* s1_b  = (const float*)d_in[28];
    const float* s2_W  = (const float*)d_in[29];
    const float* s2_b  = (const float*)d_in[30];
    const float* rW1   = (const float*)d_in[31];
    const float* rb1   = (const float*)d_in[32];
    const float* rW2   = (const float*)d_in[33];
    const float* rb2   = (const float*)d_in[34];
    const float* rg    = (const float*)d_in[35];
    const float* rbn   = (const float*)d_in[36];
    const float* out_W = (const float*)d_in[37];
    const float* out_b = (const float*)d_in[38];
    const int* subgs   = (const int*)d_in[39];
    const int* num_node= (const int*)d_in[41];
    const int* allperm = (const int*)d_in[42];

    // ---- workspace layout (peak ~122.7 MB, unchanged budget) ----
    const size_t MB_ = (size_t)512 * 128 * P_ * H_ * 2;        // 100,663,296: z2t
    char* w = (char*)d_ws;
    bf16*  mz     = (bf16*)(w);                                // region A: z2t
    bf16*  s1Wt   = (bf16*)(w + 33554432ull);                  // region A reuse (post-id2): s1_W^T bf16 32KB
    bf16*  zm     = (bf16*)(w + MB_);                          // (512,128,128) bf16 = 16.8 MB
    bf16*  WT     = (bf16*)(w + MB_ + 16777216ull);            // 8 x (128x128) bf16 transposed
    char*  wc     = w + MB_ + 16777216ull + 262144ull;
    float* hb     = (float*)(wc);                              // h (32,128,128) f32  2 MB
    float* sb2    = (float*)(wc + 2097152ull);                 // t1 / g-layer msgs    2 MB
    bf16*  adjb   = (bf16*)(wc + 2097152ull);                  // reuse sb2 region after g-layers (1 MB)
    float* hsum   = (float*)(wc + 4194304ull);                 // (512,128)
    float* hs2    = (float*)(wc + 4456448ull);                 // (512,128)
    float* pooled = (float*)(wc + 4718592ull);                 // (32,128)
    float* pooled2= (float*)(wc + 4734976ull);                 // (32,128)
    unsigned char* nbr = (unsigned char*)(wc + 4751360ull);    // 4096*48 u8
    int*   deg    = (int*)(wc + 4947968ull);                   // 4096 i32
    float* degf   = (float*)(wc + 4964352ull);                 // 4096 f32
    float* outp   = (float*)d_out;

    // prep: CSR + transposed bf16 weights
    k_csr<<<32, 128, 0, stream>>>(adj, nbr, deg, degf);
    k_wt8<<<1024, 128, 0, stream>>>(iW1, iW2, iW1 + 16384, iW2 + 16384,
                                    glW1, glW2, glW1 + 16384, glW2 + 16384, WT);

    // input embedding block: h = block(x)
    k_in_t1<<<4096, 128, 0, stream>>>(x, in_W1, in_b1, sb2);
    k_block<false, false><<<256, 128, 0, stream>>>(sb2, nullptr, hb,
        nullptr, nullptr, in_W2, in_b2, in_g, in_bn);

    // graph message passing (3 layers) on h — small, keep VALU path
    for (int l = 0; l < 3; ++l) {
        k_spmv<<<4096, 128, 0, stream>>>(adj, hb, sb2, 0);
        k_block<true, true><<<256, 128, 0, stream>>>(sb2, hb, hb,
            gW1 + l * 16384, gb1 + l * 128, gW2 + l * 16384, gb2 + l * 128,
            gg + l * 128, gbn + l * 128);
    }

    // adjacency -> bf16 (sb2 region is dead now)
    k_adjb<<<4096, 128, 0, stream>>>(adj, adjb);

    // ID layer 1 FUSED v2 (single-buffer, 36.9 KB LDS): m in-LDS -> MFMA MLP -> z2t
    k_id1_fused<<<3072, 256, 0, stream>>>(adj, degf, subgs, allperm, idemb, mz,
        WT, ib1, WT + 16384, ib2, ig, ibn);

    // ID layer 2 v9: single-buffer (36.9 KB LDS -> 2 blocks/CU) -> zm
    k_id2_v9<<<512, 256, 0, stream>>>(mz, zm, adjb, num_node, subgs, allperm, idemb,
        WT + 2 * 16384, ib1 + 128, WT + 3 * 16384, ib2 + 128, ig + 128, ibn + 128);

    // s1_W^T (into region A — z2t is dead now)
    k_wt1<<<128, 128, 0, stream>>>(s1_W, s1Wt);

    // fused: setmlp1 + 2 gl layers + node-sum -> hsum
    k_gl_fused<<<512, 256, 0, stream>>>(zm, hb, adjb, s1Wt, s1_b,
        WT + 4 * 16384, glb1, glb2, glg, glbn, hsum);

    // setmlp2 -> segment max -> setmlp3 block -> output proj
    k_gemm_relu<false, float><<<32, 128, 0, stream>>>(hsum, nullptr, hs2, s2_W, s2_b);
    k_maxpool<<<32, 128, 0, stream>>>(hs2, pooled);
    k_block<true, true><<<2, 128, 0, stream>>>(pooled, pooled, pooled2,
        rW1, rb1, rW2, rb2, rg, rbn);
    k_out<<<32, 128, 0, stream>>>(pooled2, out_W, out_b, outp);
}

// Round 16
// 589.778 us; speedup vs baseline: 1.6255x; 1.2392x over previous
//
#include <hip/hip_runtime.h>
#include <hip/hip_bf16.h>
#include <string.h>

typedef __hip_bfloat16 bf16;
typedef short v8s __attribute__((ext_vector_type(8)));
typedef float v4f __attribute__((ext_vector_type(4)));

#define H_ 128
#define P_ 6
#define K_ 4

__device__ __forceinline__ float ldf(const float* p, size_t i) { return p[i]; }
__device__ __forceinline__ float ldf(const bf16* p, size_t i) { return __bfloat162float(p[i]); }

__device__ __forceinline__ float s2f(short s) {
    unsigned int u = ((unsigned int)(unsigned short)s) << 16;
    float f; __builtin_memcpy(&f, &u, 4); return f;
}
__device__ __forceinline__ short f2s(float v) {
    bf16 h = __float2bfloat16(v);
    short s; __builtin_memcpy(&s, &h, 2); return s;
}
__device__ __forceinline__ v4f MFMA(v8s a, v8s b, v4f c) {
    return __builtin_amdgcn_mfma_f32_16x16x32_bf16(a, b, c, 0, 0, 0);
}

// ---------------- degf = adj row sums (coalesced; 0/1 entries -> exact) ----------------
__global__ __launch_bounds__(128) void k_deg(const float* __restrict__ adj, float* __restrict__ degf)
{
    __shared__ float red[128];
    const int row = blockIdx.x, t = threadIdx.x;
    red[t] = adj[(size_t)row * 128 + t];
    __syncthreads();
    for (int s = 64; s > 0; s >>= 1) {
        if (t < s) red[t] += red[t + s];
        __syncthreads();
    }
    if (t == 0) degf[row] = red[0];
}

// ---------------- adjacency -> bf16 (values are exactly 0/1) ----------------
__global__ __launch_bounds__(128) void k_adjb(const float* __restrict__ adj, bf16* __restrict__ adjb)
{
    const size_t i = (size_t)blockIdx.x * 128 + threadIdx.x;
    adjb[i] = __float2bfloat16(adj[i]);
}

// ---------------- transpose 8 (128x128) weights to bf16 WT[n][k] ----------------
__global__ __launch_bounds__(128) void k_wt8(
    const float* s0, const float* s1, const float* s2, const float* s3,
    const float* s4, const float* s5, const float* s6, const float* s7,
    bf16* __restrict__ dst)
{
    const int w = blockIdx.x >> 7, n = blockIdx.x & 127, k = threadIdx.x;
    const float* arr[8] = {s0, s1, s2, s3, s4, s5, s6, s7};
    dst[(size_t)w * 16384 + n * 128 + k] = __float2bfloat16(arr[w][k * 128 + n]);
}

// ---------------- transpose single 128x128 weight to bf16 ----------------
__global__ __launch_bounds__(128) void k_wt1(const float* __restrict__ src, bf16* __restrict__ dst)
{
    const int n = blockIdx.x, k = threadIdx.x;
    dst[n * 128 + k] = __float2bfloat16(src[k * 128 + n]);
}

// ---------------- generic VALU fused block (tail only) ----------------
template<bool DO_MM1, bool HAS_RES>
__global__ __launch_bounds__(128) void k_block(
    const float* __restrict__ in, const float* __restrict__ res, float* __restrict__ out,
    const float* __restrict__ W1, const float* __restrict__ b1,
    const float* __restrict__ W2, const float* __restrict__ b2,
    const float* __restrict__ gam, const float* __restrict__ bet)
{
    __shared__ float sA[16][136];
    __shared__ float sB[16][136];
    __shared__ float sStat[32];
    const int hd = threadIdx.x;
    const size_t row0 = (size_t)blockIdx.x * 16;
    #pragma unroll
    for (int r = 0; r < 16; ++r) sA[r][hd] = in[(row0 + r) * H_ + hd];
    __syncthreads();
    float acc[16];
    if (DO_MM1) {
        #pragma unroll
        for (int r = 0; r < 16; ++r) acc[r] = b1[hd];
        for (int k = 0; k < H_; k += 4) {
            float w0 = W1[(k+0)*H_+hd], w1 = W1[(k+1)*H_+hd], w2 = W1[(k+2)*H_+hd], w3 = W1[(k+3)*H_+hd];
            #pragma unroll
            for (int r = 0; r < 16; ++r) {
                float4 a = *(const float4*)&sA[r][k];
                acc[r] = fmaf(a.x, w0, acc[r]); acc[r] = fmaf(a.y, w1, acc[r]);
                acc[r] = fmaf(a.z, w2, acc[r]); acc[r] = fmaf(a.w, w3, acc[r]);
            }
        }
        #pragma unroll
        for (int r = 0; r < 16; ++r) sB[r][hd] = fmaxf(acc[r], 0.f);
    } else {
        #pragma unroll
        for (int r = 0; r < 16; ++r) sB[r][hd] = sA[r][hd];
    }
    __syncthreads();
    #pragma unroll
    for (int r = 0; r < 16; ++r) acc[r] = b2[hd];
    for (int k = 0; k < H_; k += 4) {
        float w0 = W2[(k+0)*H_+hd], w1 = W2[(k+1)*H_+hd], w2 = W2[(k+2)*H_+hd], w3 = W2[(k+3)*H_+hd];
        #pragma unroll
        for (int r = 0; r < 16; ++r) {
            float4 a = *(const float4*)&sB[r][k];
            acc[r] = fmaf(a.x, w0, acc[r]); acc[r] = fmaf(a.y, w1, acc[r]);
            acc[r] = fmaf(a.z, w2, acc[r]); acc[r] = fmaf(a.w, w3, acc[r]);
        }
    }
    __syncthreads();
    #pragma unroll
    for (int r = 0; r < 16; ++r) sA[r][hd] = acc[r];
    __syncthreads();
    if (hd < 16) {
        float s = 0.f, ss = 0.f;
        for (int k = 0; k < H_; ++k) { float v = sA[hd][k]; s += v; ss += v * v; }
        float mean = s * (1.f / H_);
        float var = ss * (1.f / H_) - mean * mean;
        sStat[hd] = mean; sStat[16 + hd] = rsqrtf(var + 1e-5f);
    }
    __syncthreads();
    float gv = gam[hd], bv = bet[hd];
    #pragma unroll
    for (int r = 0; r < 16; ++r) {
        float v = fmaxf((acc[r] - sStat[r]) * sStat[16 + r] * gv + bv, 0.f);
        if (HAS_RES) v += res[(row0 + r) * H_ + hd];
        out[(row0 + r) * H_ + hd] = v;
    }
}

// ---------------- gemm + bias + relu (tail only) ----------------
template<bool GATHER, typename T>
__global__ __launch_bounds__(128) void k_gemm_relu(
    const T* __restrict__ in, const float* __restrict__ res, float* __restrict__ out,
    const float* __restrict__ W, const float* __restrict__ b)
{
    __shared__ float sA[16][136];
    const int hd = threadIdx.x;
    const size_t row0 = (size_t)blockIdx.x * 16;
    #pragma unroll
    for (int r = 0; r < 16; ++r) sA[r][hd] = ldf(in, (row0 + r) * H_ + hd);
    __syncthreads();
    float acc[16];
    #pragma unroll
    for (int r = 0; r < 16; ++r) acc[r] = b[hd];
    for (int k = 0; k < H_; k += 4) {
        float w0 = W[(k+0)*H_+hd], w1 = W[(k+1)*H_+hd], w2 = W[(k+2)*H_+hd], w3 = W[(k+3)*H_+hd];
        #pragma unroll
        for (int r = 0; r < 16; ++r) {
            float4 a = *(const float4*)&sA[r][k];
            acc[r] = fmaf(a.x, w0, acc[r]); acc[r] = fmaf(a.y, w1, acc[r]);
            acc[r] = fmaf(a.z, w2, acc[r]); acc[r] = fmaf(a.w, w3, acc[r]);
        }
    }
    #pragma unroll
    for (int r = 0; r < 16; ++r) {
        size_t rr = row0 + r;
        float v = fmaxf(acc[r], 0.f);
        if (GATHER) {
            int i = (int)(rr & 127);
            int g = (int)(rr >> 11);
            v += res[((size_t)(g * 128 + i)) * H_ + hd];
        }
        out[rr * H_ + hd] = v;
    }
}

// ---------------- h-pipeline FUSED: input embed + 3 g-layers, one block per graph.
// Clone of the passing k_gl_fused structure: h f32 in registers + h^T bf16 in LDS;
// spmv M=A@h via adjb A-frags; MM1/MM2 via transposed bf16 weights; LN epilogues.
// Replaces k_in_t1, k_block<ff>, 3 x (k_spmv + k_block) and the sb2 round-trips.
__global__ __launch_bounds__(256) void k_h_fused(
    const float* __restrict__ x, const bf16* __restrict__ adjb,
    const float* __restrict__ inW1, const float* __restrict__ inb1,
    const bf16* __restrict__ inW2t, const float* __restrict__ inb2,
    const float* __restrict__ ing, const float* __restrict__ inbn,
    const bf16* __restrict__ WTg,           // gW1t[0],gW2t[0],gW1t[1],gW2t[1],gW1t[2],gW2t[2]
    const float* __restrict__ gb1, const float* __restrict__ gb2,
    const float* __restrict__ gg, const float* __restrict__ gbn,
    float* __restrict__ hb)
{
    __shared__ __align__(16) short sHsT[128][136];  // h^T bf16 [f][node]   34.8 KB
    __shared__ __align__(16) short sM[128][136];    // t1 / M / T scratch   34.8 KB
    __shared__ float sP[15][128];                   // inb2,ing,inbn + (gb1,gb2,gg,gbn)x3
    const int t = threadIdx.x;
    const int g = blockIdx.x;
    const int wave = t >> 6, lane = t & 63, quad = lane >> 4, l16 = lane & 15;
    const int wrow = wave << 5;

    for (int u = t; u < 15 * 128; u += 256) {
        const int a = u >> 7, n = u & 127;
        const float* src;
        if (a == 0) src = inb2;
        else if (a == 1) src = ing;
        else if (a == 2) src = inbn;
        else {
            const int l = (a - 3) >> 2, pp = (a - 3) & 3;
            src = (pp == 0) ? gb1 + l * 128 : (pp == 1) ? gb2 + l * 128
                : (pp == 2) ? gg + l * 128 : gbn + l * 128;
        }
        sP[a][n] = src[n];
    }

    // adjacency A-frags
    v8s aA[2][4];
    {
        const bf16* ar = adjb + (size_t)g * 16384;
        #pragma unroll
        for (int mt = 0; mt < 2; ++mt)
            #pragma unroll
            for (int kk = 0; kk < 4; ++kk)
                aA[mt][kk] = *(const v8s*)(ar + (size_t)(wrow + mt * 16 + l16) * 128 + kk * 32 + quad * 8);
    }

    // ---- t1 = relu(x*W1 + b1) into sM (wave-own rows: i = t>>1 in [wave*32, wave*32+32)) ----
    {
        const int i = t >> 1, half = (t & 1) * 64;
        const float xv = x[(size_t)g * 128 + i];
        #pragma unroll
        for (int fb = 0; fb < 64; fb += 8) {
            v8s pk;
            #pragma unroll
            for (int e = 0; e < 8; ++e)
                pk[e] = f2s(fmaxf(fmaf(xv, inW1[half + fb + e], inb1[half + fb + e]), 0.f));
            *(v8s*)&sM[i][half + fb] = pk;
        }
    }
    __syncthreads();   // sP visible (t1 rows are wave-own)

    // ---- h0 = relu(LN(t1 @ inW2 + inb2)*ing + inbn) ----
    v4f acc[2][8];
    #pragma unroll
    for (int mt = 0; mt < 2; ++mt)
        #pragma unroll
        for (int nt = 0; nt < 8; ++nt) acc[mt][nt] = (v4f){0.f, 0.f, 0.f, 0.f};
    #pragma unroll
    for (int kk = 0; kk < 4; ++kk) {
        v8s a0 = *(const v8s*)&sM[wrow + l16][kk * 32 + quad * 8];
        v8s a1 = *(const v8s*)&sM[wrow + 16 + l16][kk * 32 + quad * 8];
        #pragma unroll
        for (int nt = 0; nt < 8; ++nt) {
            v8s b = *(const v8s*)(inW2t + (nt * 16 + l16) * 128 + kk * 32 + quad * 8);
            acc[0][nt] = MFMA(a0, b, acc[0][nt]);
            acc[1][nt] = MFMA(a1, b, acc[1][nt]);
        }
    }
    float hs_reg[2][8][4];
    #pragma unroll
    for (int mt = 0; mt < 2; ++mt)
        #pragma unroll
        for (int r = 0; r < 4; ++r) {
            float s = 0.f, qq = 0.f;
            #pragma unroll
            for (int nt = 0; nt < 8; ++nt) {
                float u = acc[mt][nt][r] + sP[0][nt * 16 + l16];
                acc[mt][nt][r] = u;
                s += u; qq += u * u;
            }
            #pragma unroll
            for (int d = 1; d < 16; d <<= 1) {
                s += __shfl_xor(s, d);
                qq += __shfl_xor(qq, d);
            }
            float mn = s * (1.f / 128.f);
            float rs = rsqrtf(qq * (1.f / 128.f) - mn * mn + 1e-5f);
            const int i = wrow + mt * 16 + quad * 4 + r;
            #pragma unroll
            for (int nt = 0; nt < 8; ++nt) {
                const int n = nt * 16 + l16;
                float v = fmaxf((acc[mt][nt][r] - mn) * rs * sP[1][n] + sP[2][n], 0.f);
                hs_reg[mt][nt][r] = v;
                sHsT[n][i] = f2s(v);
            }
        }
    __syncthreads();   // h^T complete

    // ---- 3 g-layers: h += relu(LN(relu((A@h)@W1+b1)@W2+b2)*g+bn) ----
    for (int l = 0; l < 3; ++l) {
        const bf16* W1t = WTg + (size_t)(2 * l) * 16384;
        const bf16* W2t = WTg + (size_t)(2 * l + 1) * 16384;
        #pragma unroll
        for (int mt = 0; mt < 2; ++mt)
            #pragma unroll
            for (int nt = 0; nt < 8; ++nt) acc[mt][nt] = (v4f){0.f, 0.f, 0.f, 0.f};
        #pragma unroll
        for (int kk = 0; kk < 4; ++kk)
            #pragma unroll
            for (int nt = 0; nt < 8; ++nt) {
                v8s b = *(const v8s*)&sHsT[nt * 16 + l16][kk * 32 + quad * 8];
                acc[0][nt] = MFMA(aA[0][kk], b, acc[0][nt]);
                acc[1][nt] = MFMA(aA[1][kk], b, acc[1][nt]);
            }
        #pragma unroll
        for (int nt = 0; nt < 8; ++nt)
            #pragma unroll
            for (int mt = 0; mt < 2; ++mt)
                #pragma unroll
                for (int r = 0; r < 4; ++r)
                    sM[wrow + mt * 16 + quad * 4 + r][nt * 16 + l16] = f2s(acc[mt][nt][r]);
        __syncthreads();
        #pragma unroll
        for (int mt = 0; mt < 2; ++mt)
            #pragma unroll
            for (int nt = 0; nt < 8; ++nt) acc[mt][nt] = (v4f){0.f, 0.f, 0.f, 0.f};
        #pragma unroll
        for (int kk = 0; kk < 4; ++kk) {
            v8s a0 = *(const v8s*)&sM[wrow + l16][kk * 32 + quad * 8];
            v8s a1 = *(const v8s*)&sM[wrow + 16 + l16][kk * 32 + quad * 8];
            #pragma unroll
            for (int nt = 0; nt < 8; ++nt) {
                v8s b = *(const v8s*)(W1t + (nt * 16 + l16) * 128 + kk * 32 + quad * 8);
                acc[0][nt] = MFMA(a0, b, acc[0][nt]);
                acc[1][nt] = MFMA(a1, b, acc[1][nt]);
            }
        }
        #pragma unroll
        for (int nt = 0; nt < 8; ++nt) {
            float bb = sP[3 + 4 * l + 0][nt * 16 + l16];
            #pragma unroll
            for (int mt = 0; mt < 2; ++mt)
                #pragma unroll
                for (int r = 0; r < 4; ++r)
                    sM[wrow + mt * 16 + quad * 4 + r][nt * 16 + l16] = f2s(fmaxf(acc[mt][nt][r] + bb, 0.f));
        }
        #pragma unroll
        for (int mt = 0; mt < 2; ++mt)
            #pragma unroll
            for (int nt = 0; nt < 8; ++nt) acc[mt][nt] = (v4f){0.f, 0.f, 0.f, 0.f};
        #pragma unroll
        for (int kk = 0; kk < 4; ++kk) {
            v8s a0 = *(const v8s*)&sM[wrow + l16][kk * 32 + quad * 8];
            v8s a1 = *(const v8s*)&sM[wrow + 16 + l16][kk * 32 + quad * 8];
            #pragma unroll
            for (int nt = 0; nt < 8; ++nt) {
                v8s b = *(const v8s*)(W2t + (nt * 16 + l16) * 128 + kk * 32 + quad * 8);
                acc[0][nt] = MFMA(a0, b, acc[0][nt]);
                acc[1][nt] = MFMA(a1, b, acc[1][nt]);
            }
        }
        #pragma unroll
        for (int mt = 0; mt < 2; ++mt)
            #pragma unroll
            for (int r = 0; r < 4; ++r) {
                float s = 0.f, qq = 0.f;
                #pragma unroll
                for (int nt = 0; nt < 8; ++nt) {
                    float u = acc[mt][nt][r] + sP[3 + 4 * l + 1][nt * 16 + l16];
                    acc[mt][nt][r] = u;
                    s += u; qq += u * u;
                }
                #pragma unroll
                for (int d = 1; d < 16; d <<= 1) {
                    s += __shfl_xor(s, d);
                    qq += __shfl_xor(qq, d);
                }
                float mn = s * (1.f / 128.f);
                float rs = rsqrtf(qq * (1.f / 128.f) - mn * mn + 1e-5f);
                const int i = wrow + mt * 16 + quad * 4 + r;
                #pragma unroll
                for (int nt = 0; nt < 8; ++nt) {
                    const int n = nt * 16 + l16;
                    float v = fmaxf((acc[mt][nt][r] - mn) * rs * sP[3 + 4 * l + 2][n] + sP[3 + 4 * l + 3][n], 0.f);
                    float h2 = hs_reg[mt][nt][r] + v;
                    hs_reg[mt][nt][r] = h2;
                    sHsT[n][i] = f2s(h2);
                }
            }
        __syncthreads();
    }

    // ---- write h (f32, full precision residual chain) ----
    #pragma unroll
    for (int mt = 0; mt < 2; ++mt)
        #pragma unroll
        for (int nt = 0; nt < 8; ++nt)
            #pragma unroll
            for (int r = 0; r < 4; ++r) {
                const int i = wrow + mt * 16 + quad * 4 + r;
                const int n = nt * 16 + l16;
                hb[((size_t)(g * 128 + i)) * 128 + n] = hs_reg[mt][nt][r];
            }
}

// ---------------- ID layer 1 FUSED (single-buffer, passing R15) ----------------
__global__ __launch_bounds__(256) void k_id1_fused(
    const float* __restrict__ adj, const float* __restrict__ degf,
    const int* __restrict__ subgs, const int* __restrict__ allperm,
    const float* __restrict__ idemb, bf16* __restrict__ outb,
    const bf16* __restrict__ W1t, const float* __restrict__ b1,
    const bf16* __restrict__ W2t, const float* __restrict__ b2,
    const float* __restrict__ gam, const float* __restrict__ bet)
{
    __shared__ __align__(16) short sB[128][136];
    __shared__ float sE[K_][128];
    const int t = threadIdx.x;
    const int bi = blockIdx.x;
    const int b_s = bi / 6, p = bi - b_s * 6;
    const int g = b_s >> 4;
    const int wave = t >> 6, lane = t & 63;
    const int quad = lane >> 4, l16 = lane & 15;
    const int wrow = wave << 5;

    int nodeq[K_];
    #pragma unroll
    for (int q = 0; q < K_; ++q) nodeq[q] = subgs[b_s * K_ + q];

    for (int u = t; u < K_ * 128; u += 256) {
        const int q = u >> 7, f = u & 127;
        sE[q][f] = idemb[(size_t)allperm[q * P_ + p] * H_ + f] - 1.f;
    }
    __syncthreads();

    {
        const int i = t >> 1, half = (t & 1) * 64;
        const int gi = g * 128 + i;
        const float dg = degf[gi];
        float aq[K_];
        #pragma unroll
        for (int q = 0; q < K_; ++q) aq[q] = adj[(size_t)gi * 128 + nodeq[q]];
        #pragma unroll
        for (int f = 0; f < 64; ++f) {
            float v = dg;
            #pragma unroll
            for (int q = 0; q < K_; ++q) v = fmaf(aq[q], sE[q][half + f], v);
            sB[i][half + f] = f2s(v);
        }
    }
    __syncthreads();

    v4f acc[2][8];
    #pragma unroll
    for (int mt = 0; mt < 2; ++mt)
        #pragma unroll
        for (int nt = 0; nt < 8; ++nt) acc[mt][nt] = (v4f){0.f, 0.f, 0.f, 0.f};
    #pragma unroll
    for (int kk = 0; kk < 4; ++kk) {
        v8s a0 = *(const v8s*)&sB[wrow + l16][kk * 32 + quad * 8];
        v8s a1 = *(const v8s*)&sB[wrow + 16 + l16][kk * 32 + quad * 8];
        #pragma unroll
        for (int nt = 0; nt < 8; ++nt) {
            v8s b = *(const v8s*)(W1t + (nt * 16 + l16) * 128 + kk * 32 + quad * 8);
            acc[0][nt] = MFMA(a0, b, acc[0][nt]);
            acc[1][nt] = MFMA(a1, b, acc[1][nt]);
        }
    }
    #pragma unroll
    for (int nt = 0; nt < 8; ++nt) {
        float bb = b1[nt * 16 + l16];
        #pragma unroll
        for (int mt = 0; mt < 2; ++mt)
            #pragma unroll
            for (int r = 0; r < 4; ++r)
                sB[wrow + mt * 16 + quad * 4 + r][nt * 16 + l16] = f2s(fmaxf(acc[mt][nt][r] + bb, 0.f));
    }
    #pragma unroll
    for (int mt = 0; mt < 2; ++mt)
        #pragma unroll
        for (int nt = 0; nt < 8; ++nt) acc[mt][nt] = (v4f){0.f, 0.f, 0.f, 0.f};
    #pragma unroll
    for (int kk = 0; kk < 4; ++kk) {
        v8s a0 = *(const v8s*)&sB[wrow + l16][kk * 32 + quad * 8];
        v8s a1 = *(const v8s*)&sB[wrow + 16 + l16][kk * 32 + quad * 8];
        #pragma unroll
        for (int nt = 0; nt < 8; ++nt) {
            v8s b = *(const v8s*)(W2t + (nt * 16 + l16) * 128 + kk * 32 + quad * 8);
            acc[0][nt] = MFMA(a0, b, acc[0][nt]);
            acc[1][nt] = MFMA(a1, b, acc[1][nt]);
        }
    }
    float bb2[8], gv[8], bv[8];
    #pragma unroll
    for (int nt = 0; nt < 8; ++nt) {
        int n = nt * 16 + l16;
        bb2[nt] = b2[n]; gv[nt] = gam[n]; bv[nt] = bet[n];
    }
    #pragma unroll
    for (int mt = 0; mt < 2; ++mt)
        #pragma unroll
        for (int r = 0; r < 4; ++r) {
            float s = 0.f, q = 0.f;
            #pragma unroll
            for (int nt = 0; nt < 8; ++nt) {
                float u = acc[mt][nt][r] + bb2[nt];
                acc[mt][nt][r] = u;
                s += u; q += u * u;
            }
            #pragma unroll
            for (int d = 1; d < 16; d <<= 1) {
                s += __shfl_xor(s, d);
                q += __shfl_xor(q, d);
            }
            float mn = s * (1.f / 128.f);
            float rs = rsqrtf(q * (1.f / 128.f) - mn * mn + 1e-5f);
            #pragma unroll
            for (int nt = 0; nt < 8; ++nt) {
                float v = fmaxf((acc[mt][nt][r] - mn) * rs * gv[nt] + bv[nt], 0.f);
                sB[wrow + mt * 16 + quad * 4 + r][nt * 16 + l16] = f2s(v + 1.0f);
            }
        }
    __syncthreads();
    {
        const int f = t >> 1, nh = (t & 1) * 64;
        const short* flat = &sB[0][0];
        bf16* dst = outb + (size_t)bi * 16384 + (size_t)f * 128 + nh;
        #pragma unroll
        for (int u = 0; u < 8; ++u) {
            v8s pk;
            #pragma unroll
            for (int e = 0; e < 8; ++e) pk[e] = flat[(nh + u * 8 + e) * 136 + f];
            *(v8s*)(dst + u * 8) = pk;
        }
    }
}

// ---------------- ID layer 2 v9 (passing, R13) ----------------
__global__ __launch_bounds__(256) void k_id2_v9(
    const bf16* __restrict__ z2t, bf16* __restrict__ zm,
    const bf16* __restrict__ adjb, const int* __restrict__ num_node,
    const int* __restrict__ subgs, const int* __restrict__ allperm,
    const float* __restrict__ idemb,
    const bf16* __restrict__ W1t, const float* __restrict__ b1,
    const bf16* __restrict__ W2t, const float* __restrict__ b2,
    const float* __restrict__ gam, const float* __restrict__ bet)
{
    __shared__ __align__(16) short sB[128][136];
    __shared__ float sP[4][128];
    const int t = threadIdx.x;
    const int b_s = blockIdx.x;
    const int g = b_s >> 4;
    const int wave = t >> 6, lane = t & 63, quad = lane >> 4, l16 = lane & 15;
    const int wrow = wave << 5;

    #pragma unroll
    for (int u = 0; u < 2; ++u) {
        const int v = t + u * 256;
        const int a = v >> 7, n = v & 127;
        const float* src = (a == 0) ? b1 : (a == 1) ? b2 : (a == 2) ? gam : bet;
        sP[a][n] = src[n];
    }

    v8s aA[2][4];
    {
        const bf16* ar = adjb + (size_t)g * 16384;
        #pragma unroll
        for (int mt = 0; mt < 2; ++mt)
            #pragma unroll
            for (int kk = 0; kk < 4; ++kk)
                aA[mt][kk] = *(const v8s*)(ar + (size_t)(wrow + mt * 16 + l16) * 128 + kk * 32 + quad * 8);
    }
    int nodeq[K_];
    #pragma unroll
    for (int q = 0; q < K_; ++q) nodeq[q] = subgs[b_s * K_ + q];

    float macc[2][8][4];
    #pragma unroll
    for (int mt = 0; mt < 2; ++mt)
        #pragma unroll
        for (int nt = 0; nt < 8; ++nt)
            #pragma unroll
            for (int r = 0; r < 4; ++r) macc[mt][nt][r] = 0.f;

    const int sf = t >> 1, shalf = (t & 1) * 64;

    for (int p = 0; p < P_; ++p) {
        {
            const bf16* src = z2t + ((size_t)(b_s * P_ + p)) * 16384 + (size_t)sf * 128 + shalf;
            #pragma unroll
            for (int u = 0; u < 8; ++u)
                *(v8s*)&sB[sf][shalf + u * 8] = *(const v8s*)(src + u * 8);
        }
        __syncthreads();
        if (t < 128) {
            #pragma unroll
            for (int q = 0; q < K_; ++q) {
                float e = idemb[(size_t)allperm[q * P_ + p] * H_ + t] - 1.f;
                short* cell = &sB[t][nodeq[q]];
                *cell = f2s(s2f(*cell) + e);
            }
        }
        __syncthreads();
        #pragma unroll
        for (int mt = 0; mt < 2; ++mt)
            #pragma unroll
            for (int nt = 0; nt < 8; ++nt) {
                const int n = nt * 16 + l16;
                #pragma unroll
                for (int r = 0; r < 4; ++r)
                    macc[mt][nt][r] += s2f(sB[n][wrow + mt * 16 + quad * 4 + r]);
            }
        v4f acc[2][8];
        #pragma unroll
        for (int mt = 0; mt < 2; ++mt)
            #pragma unroll
            for (int nt = 0; nt < 8; ++nt) acc[mt][nt] = (v4f){0.f, 0.f, 0.f, 0.f};
        #pragma unroll
        for (int kk = 0; kk < 4; ++kk)
            #pragma unroll
            for (int nt = 0; nt < 8; ++nt) {
                v8s b = *(const v8s*)&sB[nt * 16 + l16][kk * 32 + quad * 8];
                acc[0][nt] = MFMA(aA[0][kk], b, acc[0][nt]);
                acc[1][nt] = MFMA(aA[1][kk], b, acc[1][nt]);
            }
        __syncthreads();
        #pragma unroll
        for (int nt = 0; nt < 8; ++nt)
            #pragma unroll
            for (int mt = 0; mt < 2; ++mt)
                #pragma unroll
                for (int r = 0; r < 4; ++r)
                    sB[wrow + mt * 16 + quad * 4 + r][nt * 16 + l16] = f2s(acc[mt][nt][r]);
        #pragma unroll
        for (int mt = 0; mt < 2; ++mt)
            #pragma unroll
            for (int nt = 0; nt < 8; ++nt) acc[mt][nt] = (v4f){0.f, 0.f, 0.f, 0.f};
        #pragma unroll
        for (int kk = 0; kk < 4; ++kk) {
            v8s a0 = *(const v8s*)&sB[wrow + l16][kk * 32 + quad * 8];
            v8s a1 = *(const v8s*)&sB[wrow + 16 + l16][kk * 32 + quad * 8];
            #pragma unroll
            for (int nt = 0; nt < 8; ++nt) {
                v8s b = *(const v8s*)(W1t + (nt * 16 + l16) * 128 + kk * 32 + quad * 8);
                acc[0][nt] = MFMA(a0, b, acc[0][nt]);
                acc[1][nt] = MFMA(a1, b, acc[1][nt]);
            }
        }
        #pragma unroll
        for (int nt = 0; nt < 8; ++nt) {
            float bb = sP[0][nt * 16 + l16];
            #pragma unroll
            for (int mt = 0; mt < 2; ++mt)
                #pragma unroll
                for (int r = 0; r < 4; ++r)
                    sB[wrow + mt * 16 + quad * 4 + r][nt * 16 + l16] = f2s(fmaxf(acc[mt][nt][r] + bb, 0.f));
        }
        #pragma unroll
        for (int mt = 0; mt < 2; ++mt)
            #pragma unroll
            for (int nt = 0; nt < 8; ++nt) acc[mt][nt] = (v4f){0.f, 0.f, 0.f, 0.f};
        #pragma unroll
        for (int kk = 0; kk < 4; ++kk) {
            v8s a0 = *(const v8s*)&sB[wrow + l16][kk * 32 + quad * 8];
            v8s a1 = *(const v8s*)&sB[wrow + 16 + l16][kk * 32 + quad * 8];
            #pragma unroll
            for (int nt = 0; nt < 8; ++nt) {
                v8s b = *(const v8s*)(W2t + (nt * 16 + l16) * 128 + kk * 32 + quad * 8);
                acc[0][nt] = MFMA(a0, b, acc[0][nt]);
                acc[1][nt] = MFMA(a1, b, acc[1][nt]);
            }
        }
        #pragma unroll
        for (int mt = 0; mt < 2; ++mt)
            #pragma unroll
            for (int r = 0; r < 4; ++r) {
                float s = 0.f, qq = 0.f;
                #pragma unroll
                for (int nt = 0; nt < 8; ++nt) {
                    float u = acc[mt][nt][r] + sP[1][nt * 16 + l16];
                    acc[mt][nt][r] = u;
                    s += u; qq += u * u;
                }
                #pragma unroll
                for (int d = 1; d < 16; d <<= 1) {
                    s += __shfl_xor(s, d);
                    qq += __shfl_xor(qq, d);
                }
                float mn = s * (1.f / 128.f);
                float rs = rsqrtf(qq * (1.f / 128.f) - mn * mn + 1e-5f);
                #pragma unroll
                for (int nt = 0; nt < 8; ++nt) {
                    const int n = nt * 16 + l16;
                    macc[mt][nt][r] += fmaxf((acc[mt][nt][r] - mn) * rs * sP[2][n] + sP[3][n], 0.f);
                }
            }
        __syncthreads();
    }
    const int nn = num_node[g];
    #pragma unroll
    for (int mt = 0; mt < 2; ++mt)
        #pragma unroll
        for (int nt = 0; nt < 8; ++nt)
            #pragma unroll
            for (int r = 0; r < 4; ++r) {
                const int i = wrow + mt * 16 + quad * 4 + r;
                const int n = nt * 16 + l16;
                float v = (i >= nn) ? 0.f : macc[mt][nt][r] * (1.f / 6.f);
                zm[((size_t)(b_s * 128 + i)) * 128 + n] = __float2bfloat16(v);
            }
}

// ---------------- fused gl stage (passing, R11) ----------------
__global__ __launch_bounds__(256) void k_gl_fused(
    const bf16* __restrict__ zm, const float* __restrict__ hb,
    const bf16* __restrict__ adjb,
    const bf16* __restrict__ s1Wt, const float* __restrict__ s1_b,
    const bf16* __restrict__ WTgl,
    const float* __restrict__ glb1, const float* __restrict__ glb2,
    const float* __restrict__ glg, const float* __restrict__ glbn,
    float* __restrict__ hsum)
{
    __shared__ __align__(16) short sHsT[128][136];
    __shared__ __align__(16) short sM[128][136];
    __shared__ float sP[9][128];
    const int t = threadIdx.x;
    const int b_s = blockIdx.x;
    const int g = b_s >> 4;
    const int wave = t >> 6, lane = t & 63, quad = lane >> 4, l16 = lane & 15;
    const int wrow = wave << 5;

    for (int u = t; u < 9 * 128; u += 256) {
        const int a = u >> 7, n = u & 127;
        const float* src =
            (a == 0) ? glb1 : (a == 1) ? glb2 : (a == 2) ? glg : (a == 3) ? glbn :
            (a == 4) ? glb1 + 128 : (a == 5) ? glb2 + 128 : (a == 6) ? glg + 128 :
            (a == 7) ? glbn + 128 : s1_b;
        sP[a][n] = src[n];
    }

    v8s aA[2][4];
    {
        const bf16* ar = adjb + (size_t)g * 16384;
        #pragma unroll
        for (int mt = 0; mt < 2; ++mt)
            #pragma unroll
            for (int kk = 0; kk < 4; ++kk)
                aA[mt][kk] = *(const v8s*)(ar + (size_t)(wrow + mt * 16 + l16) * 128 + kk * 32 + quad * 8);
    }

    v4f acc[2][8];
    #pragma unroll
    for (int mt = 0; mt < 2; ++mt)
        #pragma unroll
        for (int nt = 0; nt < 8; ++nt) acc[mt][nt] = (v4f){0.f, 0.f, 0.f, 0.f};
    #pragma unroll
    for (int kk = 0; kk < 4; ++kk) {
        v8s a0 = *(const v8s*)(zm + ((size_t)(b_s * 128) + wrow + l16) * 128 + kk * 32 + quad * 8);
        v8s a1 = *(const v8s*)(zm + ((size_t)(b_s * 128) + wrow + 16 + l16) * 128 + kk * 32 + quad * 8);
        #pragma unroll
        for (int nt = 0; nt < 8; ++nt) {
            v8s b = *(const v8s*)(s1Wt + (nt * 16 + l16) * 128 + kk * 32 + quad * 8);
            acc[0][nt] = MFMA(a0, b, acc[0][nt]);
            acc[1][nt] = MFMA(a1, b, acc[1][nt]);
        }
    }
    __syncthreads();
    float hs_reg[2][8][4];
    #pragma unroll
    for (int mt = 0; mt < 2; ++mt)
        #pragma unroll
        for (int nt = 0; nt < 8; ++nt)
            #pragma unroll
            for (int r = 0; r < 4; ++r) {
                const int i = wrow + mt * 16 + quad * 4 + r;
                const int n = nt * 16 + l16;
                float v = fmaxf(acc[mt][nt][r] + sP[8][n], 0.f);
                v += hb[((size_t)(g * 128 + i)) * 128 + n];
                hs_reg[mt][nt][r] = v;
                sHsT[n][i] = f2s(v);
            }
    __syncthreads();

    for (int l = 0; l < 2; ++l) {
        const bf16* W1t = WTgl + (size_t)(2 * l) * 16384;
        const bf16* W2t = WTgl + (size_t)(2 * l + 1) * 16384;
        #pragma unroll
        for (int mt = 0; mt < 2; ++mt)
            #pragma unroll
            for (int nt = 0; nt < 8; ++nt) acc[mt][nt] = (v4f){0.f, 0.f, 0.f, 0.f};
        #pragma unroll
        for (int kk = 0; kk < 4; ++kk)
            #pragma unroll
            for (int nt = 0; nt < 8; ++nt) {
                v8s b = *(const v8s*)&sHsT[nt * 16 + l16][kk * 32 + quad * 8];
                acc[0][nt] = MFMA(aA[0][kk], b, acc[0][nt]);
                acc[1][nt] = MFMA(aA[1][kk], b, acc[1][nt]);
            }
        #pragma unroll
        for (int nt = 0; nt < 8; ++nt)
            #pragma unroll
            for (int mt = 0; mt < 2; ++mt)
                #pragma unroll
                for (int r = 0; r < 4; ++r)
                    sM[wrow + mt * 16 + quad * 4 + r][nt * 16 + l16] = f2s(acc[mt][nt][r]);
        __syncthreads();
        #pragma unroll
        for (int mt = 0; mt < 2; ++mt)
            #pragma unroll
            for (int nt = 0; nt < 8; ++nt) acc[mt][nt] = (v4f){0.f, 0.f, 0.f, 0.f};
        #pragma unroll
        for (int kk = 0; kk < 4; ++kk) {
            v8s a0 = *(const v8s*)&sM[wrow + l16][kk * 32 + quad * 8];
            v8s a1 = *(const v8s*)&sM[wrow + 16 + l16][kk * 32 + quad * 8];
            #pragma unroll
            for (int nt = 0; nt < 8; ++nt) {
                v8s b = *(const v8s*)(W1t + (nt * 16 + l16) * 128 + kk * 32 + quad * 8);
                acc[0][nt] = MFMA(a0, b, acc[0][nt]);
                acc[1][nt] = MFMA(a1, b, acc[1][nt]);
            }
        }
        #pragma unroll
        for (int nt = 0; nt < 8; ++nt) {
            float bb = sP[4 * l + 0][nt * 16 + l16];
            #pragma unroll
            for (int mt = 0; mt < 2; ++mt)
                #pragma unroll
                for (int r = 0; r < 4; ++r)
                    sM[wrow + mt * 16 + quad * 4 + r][nt * 16 + l16] = f2s(fmaxf(acc[mt][nt][r] + bb, 0.f));
        }
        #pragma unroll
        for (int mt = 0; mt < 2; ++mt)
            #pragma unroll
            for (int nt = 0; nt < 8; ++nt) acc[mt][nt] = (v4f){0.f, 0.f, 0.f, 0.f};
        #pragma unroll
        for (int kk = 0; kk < 4; ++kk) {
            v8s a0 = *(const v8s*)&sM[wrow + l16][kk * 32 + quad * 8];
            v8s a1 = *(const v8s*)&sM[wrow + 16 + l16][kk * 32 + quad * 8];
            #pragma unroll
            for (int nt = 0; nt < 8; ++nt) {
                v8s b = *(const v8s*)(W2t + (nt * 16 + l16) * 128 + kk * 32 + quad * 8);
                acc[0][nt] = MFMA(a0, b, acc[0][nt]);
                acc[1][nt] = MFMA(a1, b, acc[1][nt]);
            }
        }
        #pragma unroll
        for (int mt = 0; mt < 2; ++mt)
            #pragma unroll
            for (int r = 0; r < 4; ++r) {
                float s = 0.f, qq = 0.f;
                #pragma unroll
                for (int nt = 0; nt < 8; ++nt) {
                    float u = acc[mt][nt][r] + sP[4 * l + 1][nt * 16 + l16];
                    acc[mt][nt][r] = u;
                    s += u; qq += u * u;
                }
                #pragma unroll
                for (int d = 1; d < 16; d <<= 1) {
                    s += __shfl_xor(s, d);
                    qq += __shfl_xor(qq, d);
                }
                float mn = s * (1.f / 128.f);
                float rs = rsqrtf(qq * (1.f / 128.f) - mn * mn + 1e-5f);
                const int i = wrow + mt * 16 + quad * 4 + r;
                #pragma unroll
                for (int nt = 0; nt < 8; ++nt) {
                    const int n = nt * 16 + l16;
                    float v = fmaxf((acc[mt][nt][r] - mn) * rs * sP[4 * l + 2][n] + sP[4 * l + 3][n], 0.f);
                    float h2 = hs_reg[mt][nt][r] + v;
                    hs_reg[mt][nt][r] = h2;
                    sHsT[n][i] = f2s(h2);
                }
            }
        __syncthreads();
    }

    float* sRedf = (float*)&sM[0][0];
    #pragma unroll
    for (int nt = 0; nt < 8; ++nt) {
        float part = 0.f;
        #pragma unroll
        for (int mt = 0; mt < 2; ++mt)
            #pragma unroll
            for (int r = 0; r < 4; ++r) part += hs_reg[mt][nt][r];
        sRedf[(wave * 4 + quad) * 128 + nt * 16 + l16] = part;
    }
    __syncthreads();
    if (t < 128) {
        float s = 0.f;
        #pragma unroll
        for (int r = 0; r < 16; ++r) s += sRedf[r * 128 + t];
        hsum[(size_t)b_s * 128 + t] = s;
    }
}

// ---------------- segment max over 16 subgraphs per graph ----------------
__global__ __launch_bounds__(128) void k_maxpool(const float* __restrict__ hs2, float* __restrict__ pooled)
{
    const int g = blockIdx.x, hd = threadIdx.x;
    float m = -INFINITY;
    for (int s = 0; s < 16; ++s) m = fmaxf(m, hs2[((size_t)(g * 16 + s)) * H_ + hd]);
    pooled[(size_t)g * H_ + hd] = m;
}

// ---------------- final projection ----------------
__global__ __launch_bounds__(128) void k_out(const float* __restrict__ pooled2,
    const float* __restrict__ out_W, const float* __restrict__ out_b, float* __restrict__ out)
{
    __shared__ float red[128];
    const int g = blockIdx.x, hd = threadIdx.x;
    red[hd] = pooled2[(size_t)g * H_ + hd] * out_W[hd];
    __syncthreads();
    for (int s = 64; s > 0; s >>= 1) {
        if (hd < s) red[hd] += red[hd + s];
        __syncthreads();
    }
    if (hd == 0) out[g] = red[0] + out_b[0];
}

extern "C" void kernel_launch(void* const* d_in, const int* in_sizes, int n_in,
                              void* d_out, int out_size, void* d_ws, size_t ws_size,
                              hipStream_t stream)
{
    (void)in_sizes; (void)n_in; (void)out_size; (void)ws_size;
    const float* x     = (const float*)d_in[0];
    const float* adj   = (const float*)d_in[1];
    const float* idemb = (const float*)d_in[2];
    const float* in_W1 = (const float*)d_in[3];
    const float* in_b1 = (const float*)d_in[4];
    const float* in_W2 = (const float*)d_in[5];
    const float* in_b2 = (const float*)d_in[6];
    const float* in_g  = (const float*)d_in[7];
    const float* in_bn = (const float*)d_in[8];
    const float* gW1   = (const float*)d_in[9];
    const float* gb1   = (const float*)d_in[10];
    const float* gW2   = (const float*)d_in[11];
    const float* gb2   = (const float*)d_in[12];
    const float* gg    = (const float*)d_in[13];
    const float* gbn   = (const float*)d_in[14];
    const float* iW1   = (const float*)d_in[15];
    const float* ib1   = (const float*)d_in[16];
    const float* iW2   = (const float*)d_in[17];
    const float* ib2   = (const float*)d_in[18];
    const float* ig    = (const float*)d_in[19];
    const float* ibn   = (const float*)d_in[20];
    const float* glW1  = (const float*)d_in[21];
    const float* glb1  = (const float*)d_in[22];
    const float* glW2  = (const float*)d_in[23];
    const float* glb2  = (const float*)d_in[24];
    const float* glg   = (const float*)d_in[25];
    const float* glbn  = (const float*)d_in[26];
    const float* s1_W  = (const float*)d_in[27];
    const float* s1_b  = (const float*)d_in[28];
    const float* s2_W  = (const float*)d_in[29];
    const float* s2_b  = (const float*)d_in[30];
    const float* rW1   = (const float*)d_in[31];
    const float* rb1   = (const float*)d_in[32];
    const float* rW2   = (const float*)d_in[33];
    const float* rb2   = (const float*)d_in[34];
    const float* rg    = (const float*)d_in[35];
    const float* rbn   = (const float*)d_in[36];
    const float* out_W = (const float*)d_in[37];
    const float* out_b = (const float*)d_in[38];
    const int* subgs   = (const int*)d_in[39];
    const int* num_node= (const int*)d_in[41];
    const int* allperm = (const int*)d_in[42];

    // ---- workspace layout (unchanged budget) ----
    const size_t MB_ = (size_t)512 * 128 * P_ * H_ * 2;        // 100,663,296: z2t
    char* w = (char*)d_ws;
    bf16*  mz     = (bf16*)(w);                                // region A: z2t
    bf16*  s1Wt   = (bf16*)(w + 33554432ull);                  // region A reuse (post-id2): s1_W^T bf16
    bf16*  zm     = (bf16*)(w + MB_);                          // (512,128,128) bf16 = 16.8 MB
    bf16*  WT     = (bf16*)(w + MB_ + 16777216ull);            // 8 x (128x128) bf16 transposed
    char*  wc     = w + MB_ + 16777216ull + 262144ull;
    float* hb     = (float*)(wc);                              // h (32,128,128) f32  2 MB
    bf16*  adjb   = (bf16*)(wc + 2097152ull);                  // 1 MB (old sb2 region)
    bf16*  WT2    = (bf16*)(wc + 3145728ull);                  // 8 x 32KB = 256 KB (old sb2 tail)
    float* hsum   = (float*)(wc + 4194304ull);                 // (512,128)
    float* hs2    = (float*)(wc + 4456448ull);                 // (512,128)
    float* pooled = (float*)(wc + 4718592ull);                 // (32,128)
    float* pooled2= (float*)(wc + 4734976ull);                 // (32,128)
    float* degf   = (float*)(wc + 4964352ull);                 // 4096 f32
    float* outp   = (float*)d_out;

    // prep: degf + transposed bf16 weights + adjb
    k_deg<<<4096, 128, 0, stream>>>(adj, degf);
    k_wt8<<<1024, 128, 0, stream>>>(iW1, iW2, iW1 + 16384, iW2 + 16384,
                                    glW1, glW2, glW1 + 16384, glW2 + 16384, WT);
    k_wt8<<<1024, 128, 0, stream>>>(in_W2, gW1, gW2, gW1 + 16384,
                                    gW2 + 16384, gW1 + 32768, gW2 + 32768, in_W2, WT2);
    k_adjb<<<4096, 128, 0, stream>>>(adj, adjb);

    // h pipeline fused: input embed + 3 g-layers -> hb
    k_h_fused<<<32, 256, 0, stream>>>(x, adjb, in_W1, in_b1,
        WT2, in_b2, in_g, in_bn,
        WT2 + 16384, gb1, gb2, gg, gbn, hb);

    // ID layer 1 FUSED (single-buffer): m in-LDS -> MFMA MLP -> z2t
    k_id1_fused<<<3072, 256, 0, stream>>>(adj, degf, subgs, allperm, idemb, mz,
        WT, ib1, WT + 16384, ib2, ig, ibn);

    // ID layer 2 v9 -> zm
    k_id2_v9<<<512, 256, 0, stream>>>(mz, zm, adjb, num_node, subgs, allperm, idemb,
        WT + 2 * 16384, ib1 + 128, WT + 3 * 16384, ib2 + 128, ig + 128, ibn + 128);

    // s1_W^T (into region A — z2t is dead now)
    k_wt1<<<128, 128, 0, stream>>>(s1_W, s1Wt);

    // fused: setmlp1 + 2 gl layers + node-sum -> hsum
    k_gl_fused<<<512, 256, 0, stream>>>(zm, hb, adjb, s1Wt, s1_b,
        WT + 4 * 16384, glb1, glb2, glg, glbn, hsum);

    // setmlp2 -> segment max -> setmlp3 block -> output proj
    k_gemm_relu<false, float><<<32, 128, 0, stream>>>(hsum, nullptr, hs2, s2_W, s2_b);
    k_maxpool<<<32, 128, 0, stream>>>(hs2, pooled);
    k_block<true, true><<<2, 128, 0, stream>>>(pooled, pooled, pooled2,
        rW1, rb1, rW2, rb2, rg, rbn);
    k_out<<<32, 128, 0, stream>>>(pooled2, out_W, out_b, outp);
}

// Round 17
// 564.904 us; speedup vs baseline: 1.6971x; 1.0440x over previous
//
#include <hip/hip_runtime.h>
#include <hip/hip_bf16.h>
#include <string.h>

typedef __hip_bfloat16 bf16;
typedef short v8s __attribute__((ext_vector_type(8)));
typedef float v4f __attribute__((ext_vector_type(4)));

#define H_ 128
#define P_ 6
#define K_ 4

__device__ __forceinline__ float s2f(short s) {
    unsigned int u = ((unsigned int)(unsigned short)s) << 16;
    float f; __builtin_memcpy(&f, &u, 4); return f;
}
__device__ __forceinline__ short f2s(float v) {
    bf16 h = __float2bfloat16(v);
    short s; __builtin_memcpy(&s, &h, 2); return s;
}
__device__ __forceinline__ v4f MFMA(v8s a, v8s b, v4f c) {
    return __builtin_amdgcn_mfma_f32_16x16x32_bf16(a, b, c, 0, 0, 0);
}

// ---------------- degf = adj row sums (coalesced; 0/1 entries -> exact) ----------------
__global__ __launch_bounds__(128) void k_deg(const float* __restrict__ adj, float* __restrict__ degf)
{
    __shared__ float red[128];
    const int row = blockIdx.x, t = threadIdx.x;
    red[t] = adj[(size_t)row * 128 + t];
    __syncthreads();
    for (int s = 64; s > 0; s >>= 1) {
        if (t < s) red[t] += red[t + s];
        __syncthreads();
    }
    if (t == 0) degf[row] = red[0];
}

// ---------------- adjacency -> bf16 (values are exactly 0/1) ----------------
__global__ __launch_bounds__(128) void k_adjb(const float* __restrict__ adj, bf16* __restrict__ adjb)
{
    const size_t i = (size_t)blockIdx.x * 128 + threadIdx.x;
    adjb[i] = __float2bfloat16(adj[i]);
}

// ---------------- transpose 8 (128x128) weights to bf16 WT[n][k] ----------------
__global__ __launch_bounds__(128) void k_wt8(
    const float* s0, const float* s1, const float* s2, const float* s3,
    const float* s4, const float* s5, const float* s6, const float* s7,
    bf16* __restrict__ dst)
{
    const int w = blockIdx.x >> 7, n = blockIdx.x & 127, k = threadIdx.x;
    const float* arr[8] = {s0, s1, s2, s3, s4, s5, s6, s7};
    dst[(size_t)w * 16384 + n * 128 + k] = __float2bfloat16(arr[w][k * 128 + n]);
}

// ---------------- transpose single 128x128 weight to bf16 ----------------
__global__ __launch_bounds__(128) void k_wt1(const float* __restrict__ src, bf16* __restrict__ dst)
{
    const int n = blockIdx.x, k = threadIdx.x;
    dst[n * 128 + k] = __float2bfloat16(src[k * 128 + n]);
}

// ---------------- h-pipeline FUSED (passing, R16) ----------------
__global__ __launch_bounds__(256) void k_h_fused(
    const float* __restrict__ x, const bf16* __restrict__ adjb,
    const float* __restrict__ inW1, const float* __restrict__ inb1,
    const bf16* __restrict__ inW2t, const float* __restrict__ inb2,
    const float* __restrict__ ing, const float* __restrict__ inbn,
    const bf16* __restrict__ WTg,
    const float* __restrict__ gb1, const float* __restrict__ gb2,
    const float* __restrict__ gg, const float* __restrict__ gbn,
    float* __restrict__ hb)
{
    __shared__ __align__(16) short sHsT[128][136];
    __shared__ __align__(16) short sM[128][136];
    __shared__ float sP[15][128];
    const int t = threadIdx.x;
    const int g = blockIdx.x;
    const int wave = t >> 6, lane = t & 63, quad = lane >> 4, l16 = lane & 15;
    const int wrow = wave << 5;

    for (int u = t; u < 15 * 128; u += 256) {
        const int a = u >> 7, n = u & 127;
        const float* src;
        if (a == 0) src = inb2;
        else if (a == 1) src = ing;
        else if (a == 2) src = inbn;
        else {
            const int l = (a - 3) >> 2, pp = (a - 3) & 3;
            src = (pp == 0) ? gb1 + l * 128 : (pp == 1) ? gb2 + l * 128
                : (pp == 2) ? gg + l * 128 : gbn + l * 128;
        }
        sP[a][n] = src[n];
    }

    v8s aA[2][4];
    {
        const bf16* ar = adjb + (size_t)g * 16384;
        #pragma unroll
        for (int mt = 0; mt < 2; ++mt)
            #pragma unroll
            for (int kk = 0; kk < 4; ++kk)
                aA[mt][kk] = *(const v8s*)(ar + (size_t)(wrow + mt * 16 + l16) * 128 + kk * 32 + quad * 8);
    }

    {
        const int i = t >> 1, half = (t & 1) * 64;
        const float xv = x[(size_t)g * 128 + i];
        #pragma unroll
        for (int fb = 0; fb < 64; fb += 8) {
            v8s pk;
            #pragma unroll
            for (int e = 0; e < 8; ++e)
                pk[e] = f2s(fmaxf(fmaf(xv, inW1[half + fb + e], inb1[half + fb + e]), 0.f));
            *(v8s*)&sM[i][half + fb] = pk;
        }
    }
    __syncthreads();

    v4f acc[2][8];
    #pragma unroll
    for (int mt = 0; mt < 2; ++mt)
        #pragma unroll
        for (int nt = 0; nt < 8; ++nt) acc[mt][nt] = (v4f){0.f, 0.f, 0.f, 0.f};
    #pragma unroll
    for (int kk = 0; kk < 4; ++kk) {
        v8s a0 = *(const v8s*)&sM[wrow + l16][kk * 32 + quad * 8];
        v8s a1 = *(const v8s*)&sM[wrow + 16 + l16][kk * 32 + quad * 8];
        #pragma unroll
        for (int nt = 0; nt < 8; ++nt) {
            v8s b = *(const v8s*)(inW2t + (nt * 16 + l16) * 128 + kk * 32 + quad * 8);
            acc[0][nt] = MFMA(a0, b, acc[0][nt]);
            acc[1][nt] = MFMA(a1, b, acc[1][nt]);
        }
    }
    float hs_reg[2][8][4];
    #pragma unroll
    for (int mt = 0; mt < 2; ++mt)
        #pragma unroll
        for (int r = 0; r < 4; ++r) {
            float s = 0.f, qq = 0.f;
            #pragma unroll
            for (int nt = 0; nt < 8; ++nt) {
                float u = acc[mt][nt][r] + sP[0][nt * 16 + l16];
                acc[mt][nt][r] = u;
                s += u; qq += u * u;
            }
            #pragma unroll
            for (int d = 1; d < 16; d <<= 1) {
                s += __shfl_xor(s, d);
                qq += __shfl_xor(qq, d);
            }
            float mn = s * (1.f / 128.f);
            float rs = rsqrtf(qq * (1.f / 128.f) - mn * mn + 1e-5f);
            const int i = wrow + mt * 16 + quad * 4 + r;
            #pragma unroll
            for (int nt = 0; nt < 8; ++nt) {
                const int n = nt * 16 + l16;
                float v = fmaxf((acc[mt][nt][r] - mn) * rs * sP[1][n] + sP[2][n], 0.f);
                hs_reg[mt][nt][r] = v;
                sHsT[n][i] = f2s(v);
            }
        }
    __syncthreads();

    for (int l = 0; l < 3; ++l) {
        const bf16* W1t = WTg + (size_t)(2 * l) * 16384;
        const bf16* W2t = WTg + (size_t)(2 * l + 1) * 16384;
        #pragma unroll
        for (int mt = 0; mt < 2; ++mt)
            #pragma unroll
            for (int nt = 0; nt < 8; ++nt) acc[mt][nt] = (v4f){0.f, 0.f, 0.f, 0.f};
        #pragma unroll
        for (int kk = 0; kk < 4; ++kk)
            #pragma unroll
            for (int nt = 0; nt < 8; ++nt) {
                v8s b = *(const v8s*)&sHsT[nt * 16 + l16][kk * 32 + quad * 8];
                acc[0][nt] = MFMA(aA[0][kk], b, acc[0][nt]);
                acc[1][nt] = MFMA(aA[1][kk], b, acc[1][nt]);
            }
        #pragma unroll
        for (int nt = 0; nt < 8; ++nt)
            #pragma unroll
            for (int mt = 0; mt < 2; ++mt)
                #pragma unroll
                for (int r = 0; r < 4; ++r)
                    sM[wrow + mt * 16 + quad * 4 + r][nt * 16 + l16] = f2s(acc[mt][nt][r]);
        __syncthreads();
        #pragma unroll
        for (int mt = 0; mt < 2; ++mt)
            #pragma unroll
            for (int nt = 0; nt < 8; ++nt) acc[mt][nt] = (v4f){0.f, 0.f, 0.f, 0.f};
        #pragma unroll
        for (int kk = 0; kk < 4; ++kk) {
            v8s a0 = *(const v8s*)&sM[wrow + l16][kk * 32 + quad * 8];
            v8s a1 = *(const v8s*)&sM[wrow + 16 + l16][kk * 32 + quad * 8];
            #pragma unroll
            for (int nt = 0; nt < 8; ++nt) {
                v8s b = *(const v8s*)(W1t + (nt * 16 + l16) * 128 + kk * 32 + quad * 8);
                acc[0][nt] = MFMA(a0, b, acc[0][nt]);
                acc[1][nt] = MFMA(a1, b, acc[1][nt]);
            }
        }
        #pragma unroll
        for (int nt = 0; nt < 8; ++nt) {
            float bb = sP[3 + 4 * l + 0][nt * 16 + l16];
            #pragma unroll
            for (int mt = 0; mt < 2; ++mt)
                #pragma unroll
                for (int r = 0; r < 4; ++r)
                    sM[wrow + mt * 16 + quad * 4 + r][nt * 16 + l16] = f2s(fmaxf(acc[mt][nt][r] + bb, 0.f));
        }
        #pragma unroll
        for (int mt = 0; mt < 2; ++mt)
            #pragma unroll
            for (int nt = 0; nt < 8; ++nt) acc[mt][nt] = (v4f){0.f, 0.f, 0.f, 0.f};
        #pragma unroll
        for (int kk = 0; kk < 4; ++kk) {
            v8s a0 = *(const v8s*)&sM[wrow + l16][kk * 32 + quad * 8];
            v8s a1 = *(const v8s*)&sM[wrow + 16 + l16][kk * 32 + quad * 8];
            #pragma unroll
            for (int nt = 0; nt < 8; ++nt) {
                v8s b = *(const v8s*)(W2t + (nt * 16 + l16) * 128 + kk * 32 + quad * 8);
                acc[0][nt] = MFMA(a0, b, acc[0][nt]);
                acc[1][nt] = MFMA(a1, b, acc[1][nt]);
            }
        }
        #pragma unroll
        for (int mt = 0; mt < 2; ++mt)
            #pragma unroll
            for (int r = 0; r < 4; ++r) {
                float s = 0.f, qq = 0.f;
                #pragma unroll
                for (int nt = 0; nt < 8; ++nt) {
                    float u = acc[mt][nt][r] + sP[3 + 4 * l + 1][nt * 16 + l16];
                    acc[mt][nt][r] = u;
                    s += u; qq += u * u;
                }
                #pragma unroll
                for (int d = 1; d < 16; d <<= 1) {
                    s += __shfl_xor(s, d);
                    qq += __shfl_xor(qq, d);
                }
                float mn = s * (1.f / 128.f);
                float rs = rsqrtf(qq * (1.f / 128.f) - mn * mn + 1e-5f);
                const int i = wrow + mt * 16 + quad * 4 + r;
                #pragma unroll
                for (int nt = 0; nt < 8; ++nt) {
                    const int n = nt * 16 + l16;
                    float v = fmaxf((acc[mt][nt][r] - mn) * rs * sP[3 + 4 * l + 2][n] + sP[3 + 4 * l + 3][n], 0.f);
                    float h2 = hs_reg[mt][nt][r] + v;
                    hs_reg[mt][nt][r] = h2;
                    sHsT[n][i] = f2s(h2);
                }
            }
        __syncthreads();
    }

    #pragma unroll
    for (int mt = 0; mt < 2; ++mt)
        #pragma unroll
        for (int nt = 0; nt < 8; ++nt)
            #pragma unroll
            for (int r = 0; r < 4; ++r) {
                const int i = wrow + mt * 16 + quad * 4 + r;
                const int n = nt * 16 + l16;
                hb[((size_t)(g * 128 + i)) * 128 + n] = hs_reg[mt][nt][r];
            }
}

// ---------------- ID layer 1 FUSED (single-buffer, passing R15/R16) ----------------
__global__ __launch_bounds__(256) void k_id1_fused(
    const float* __restrict__ adj, const float* __restrict__ degf,
    const int* __restrict__ subgs, const int* __restrict__ allperm,
    const float* __restrict__ idemb, bf16* __restrict__ outb,
    const bf16* __restrict__ W1t, const float* __restrict__ b1,
    const bf16* __restrict__ W2t, const float* __restrict__ b2,
    const float* __restrict__ gam, const float* __restrict__ bet)
{
    __shared__ __align__(16) short sB[128][136];
    __shared__ float sE[K_][128];
    const int t = threadIdx.x;
    const int bi = blockIdx.x;
    const int b_s = bi / 6, p = bi - b_s * 6;
    const int g = b_s >> 4;
    const int wave = t >> 6, lane = t & 63;
    const int quad = lane >> 4, l16 = lane & 15;
    const int wrow = wave << 5;

    int nodeq[K_];
    #pragma unroll
    for (int q = 0; q < K_; ++q) nodeq[q] = subgs[b_s * K_ + q];

    for (int u = t; u < K_ * 128; u += 256) {
        const int q = u >> 7, f = u & 127;
        sE[q][f] = idemb[(size_t)allperm[q * P_ + p] * H_ + f] - 1.f;
    }
    __syncthreads();

    {
        const int i = t >> 1, half = (t & 1) * 64;
        const int gi = g * 128 + i;
        const float dg = degf[gi];
        float aq[K_];
        #pragma unroll
        for (int q = 0; q < K_; ++q) aq[q] = adj[(size_t)gi * 128 + nodeq[q]];
        #pragma unroll
        for (int f = 0; f < 64; ++f) {
            float v = dg;
            #pragma unroll
            for (int q = 0; q < K_; ++q) v = fmaf(aq[q], sE[q][half + f], v);
            sB[i][half + f] = f2s(v);
        }
    }
    __syncthreads();

    v4f acc[2][8];
    #pragma unroll
    for (int mt = 0; mt < 2; ++mt)
        #pragma unroll
        for (int nt = 0; nt < 8; ++nt) acc[mt][nt] = (v4f){0.f, 0.f, 0.f, 0.f};
    #pragma unroll
    for (int kk = 0; kk < 4; ++kk) {
        v8s a0 = *(const v8s*)&sB[wrow + l16][kk * 32 + quad * 8];
        v8s a1 = *(const v8s*)&sB[wrow + 16 + l16][kk * 32 + quad * 8];
        #pragma unroll
        for (int nt = 0; nt < 8; ++nt) {
            v8s b = *(const v8s*)(W1t + (nt * 16 + l16) * 128 + kk * 32 + quad * 8);
            acc[0][nt] = MFMA(a0, b, acc[0][nt]);
            acc[1][nt] = MFMA(a1, b, acc[1][nt]);
        }
    }
    #pragma unroll
    for (int nt = 0; nt < 8; ++nt) {
        float bb = b1[nt * 16 + l16];
        #pragma unroll
        for (int mt = 0; mt < 2; ++mt)
            #pragma unroll
            for (int r = 0; r < 4; ++r)
                sB[wrow + mt * 16 + quad * 4 + r][nt * 16 + l16] = f2s(fmaxf(acc[mt][nt][r] + bb, 0.f));
    }
    #pragma unroll
    for (int mt = 0; mt < 2; ++mt)
        #pragma unroll
        for (int nt = 0; nt < 8; ++nt) acc[mt][nt] = (v4f){0.f, 0.f, 0.f, 0.f};
    #pragma unroll
    for (int kk = 0; kk < 4; ++kk) {
        v8s a0 = *(const v8s*)&sB[wrow + l16][kk * 32 + quad * 8];
        v8s a1 = *(const v8s*)&sB[wrow + 16 + l16][kk * 32 + quad * 8];
        #pragma unroll
        for (int nt = 0; nt < 8; ++nt) {
            v8s b = *(const v8s*)(W2t + (nt * 16 + l16) * 128 + kk * 32 + quad * 8);
            acc[0][nt] = MFMA(a0, b, acc[0][nt]);
            acc[1][nt] = MFMA(a1, b, acc[1][nt]);
        }
    }
    float bb2[8], gv[8], bv[8];
    #pragma unroll
    for (int nt = 0; nt < 8; ++nt) {
        int n = nt * 16 + l16;
        bb2[nt] = b2[n]; gv[nt] = gam[n]; bv[nt] = bet[n];
    }
    #pragma unroll
    for (int mt = 0; mt < 2; ++mt)
        #pragma unroll
        for (int r = 0; r < 4; ++r) {
            float s = 0.f, q = 0.f;
            #pragma unroll
            for (int nt = 0; nt < 8; ++nt) {
                float u = acc[mt][nt][r] + bb2[nt];
                acc[mt][nt][r] = u;
                s += u; q += u * u;
            }
            #pragma unroll
            for (int d = 1; d < 16; d <<= 1) {
                s += __shfl_xor(s, d);
                q += __shfl_xor(q, d);
            }
            float mn = s * (1.f / 128.f);
            float rs = rsqrtf(q * (1.f / 128.f) - mn * mn + 1e-5f);
            #pragma unroll
            for (int nt = 0; nt < 8; ++nt) {
                float v = fmaxf((acc[mt][nt][r] - mn) * rs * gv[nt] + bv[nt], 0.f);
                sB[wrow + mt * 16 + quad * 4 + r][nt * 16 + l16] = f2s(v + 1.0f);
            }
        }
    __syncthreads();
    {
        const int f = t >> 1, nh = (t & 1) * 64;
        const short* flat = &sB[0][0];
        bf16* dst = outb + (size_t)bi * 16384 + (size_t)f * 128 + nh;
        #pragma unroll
        for (int u = 0; u < 8; ++u) {
            v8s pk;
            #pragma unroll
            for (int e = 0; e < 8; ++e) pk[e] = flat[(nh + u * 8 + e) * 136 + f];
            *(v8s*)(dst + u * 8) = pk;
        }
    }
}

// ---------------- ID layer 2 v9 (passing, R13) ----------------
__global__ __launch_bounds__(256) void k_id2_v9(
    const bf16* __restrict__ z2t, bf16* __restrict__ zm,
    const bf16* __restrict__ adjb, const int* __restrict__ num_node,
    const int* __restrict__ subgs, const int* __restrict__ allperm,
    const float* __restrict__ idemb,
    const bf16* __restrict__ W1t, const float* __restrict__ b1,
    const bf16* __restrict__ W2t, const float* __restrict__ b2,
    const float* __restrict__ gam, const float* __restrict__ bet)
{
    __shared__ __align__(16) short sB[128][136];
    __shared__ float sP[4][128];
    const int t = threadIdx.x;
    const int b_s = blockIdx.x;
    const int g = b_s >> 4;
    const int wave = t >> 6, lane = t & 63, quad = lane >> 4, l16 = lane & 15;
    const int wrow = wave << 5;

    #pragma unroll
    for (int u = 0; u < 2; ++u) {
        const int v = t + u * 256;
        const int a = v >> 7, n = v & 127;
        const float* src = (a == 0) ? b1 : (a == 1) ? b2 : (a == 2) ? gam : bet;
        sP[a][n] = src[n];
    }

    v8s aA[2][4];
    {
        const bf16* ar = adjb + (size_t)g * 16384;
        #pragma unroll
        for (int mt = 0; mt < 2; ++mt)
            #pragma unroll
            for (int kk = 0; kk < 4; ++kk)
                aA[mt][kk] = *(const v8s*)(ar + (size_t)(wrow + mt * 16 + l16) * 128 + kk * 32 + quad * 8);
    }
    int nodeq[K_];
    #pragma unroll
    for (int q = 0; q < K_; ++q) nodeq[q] = subgs[b_s * K_ + q];

    float macc[2][8][4];
    #pragma unroll
    for (int mt = 0; mt < 2; ++mt)
        #pragma unroll
        for (int nt = 0; nt < 8; ++nt)
            #pragma unroll
            for (int r = 0; r < 4; ++r) macc[mt][nt][r] = 0.f;

    const int sf = t >> 1, shalf = (t & 1) * 64;

    for (int p = 0; p < P_; ++p) {
        {
            const bf16* src = z2t + ((size_t)(b_s * P_ + p)) * 16384 + (size_t)sf * 128 + shalf;
            #pragma unroll
            for (int u = 0; u < 8; ++u)
                *(v8s*)&sB[sf][shalf + u * 8] = *(const v8s*)(src + u * 8);
        }
        __syncthreads();
        if (t < 128) {
            #pragma unroll
            for (int q = 0; q < K_; ++q) {
                float e = idemb[(size_t)allperm[q * P_ + p] * H_ + t] - 1.f;
                short* cell = &sB[t][nodeq[q]];
                *cell = f2s(s2f(*cell) + e);
            }
        }
        __syncthreads();
        #pragma unroll
        for (int mt = 0; mt < 2; ++mt)
            #pragma unroll
            for (int nt = 0; nt < 8; ++nt) {
                const int n = nt * 16 + l16;
                #pragma unroll
                for (int r = 0; r < 4; ++r)
                    macc[mt][nt][r] += s2f(sB[n][wrow + mt * 16 + quad * 4 + r]);
            }
        v4f acc[2][8];
        #pragma unroll
        for (int mt = 0; mt < 2; ++mt)
            #pragma unroll
            for (int nt = 0; nt < 8; ++nt) acc[mt][nt] = (v4f){0.f, 0.f, 0.f, 0.f};
        #pragma unroll
        for (int kk = 0; kk < 4; ++kk)
            #pragma unroll
            for (int nt = 0; nt < 8; ++nt) {
                v8s b = *(const v8s*)&sB[nt * 16 + l16][kk * 32 + quad * 8];
                acc[0][nt] = MFMA(aA[0][kk], b, acc[0][nt]);
                acc[1][nt] = MFMA(aA[1][kk], b, acc[1][nt]);
            }
        __syncthreads();
        #pragma unroll
        for (int nt = 0; nt < 8; ++nt)
            #pragma unroll
            for (int mt = 0; mt < 2; ++mt)
                #pragma unroll
                for (int r = 0; r < 4; ++r)
                    sB[wrow + mt * 16 + quad * 4 + r][nt * 16 + l16] = f2s(acc[mt][nt][r]);
        #pragma unroll
        for (int mt = 0; mt < 2; ++mt)
            #pragma unroll
            for (int nt = 0; nt < 8; ++nt) acc[mt][nt] = (v4f){0.f, 0.f, 0.f, 0.f};
        #pragma unroll
        for (int kk = 0; kk < 4; ++kk) {
            v8s a0 = *(const v8s*)&sB[wrow + l16][kk * 32 + quad * 8];
            v8s a1 = *(const v8s*)&sB[wrow + 16 + l16][kk * 32 + quad * 8];
            #pragma unroll
            for (int nt = 0; nt < 8; ++nt) {
                v8s b = *(const v8s*)(W1t + (nt * 16 + l16) * 128 + kk * 32 + quad * 8);
                acc[0][nt] = MFMA(a0, b, acc[0][nt]);
                acc[1][nt] = MFMA(a1, b, acc[1][nt]);
            }
        }
        #pragma unroll
        for (int nt = 0; nt < 8; ++nt) {
            float bb = sP[0][nt * 16 + l16];
            #pragma unroll
            for (int mt = 0; mt < 2; ++mt)
                #pragma unroll
                for (int r = 0; r < 4; ++r)
                    sB[wrow + mt * 16 + quad * 4 + r][nt * 16 + l16] = f2s(fmaxf(acc[mt][nt][r] + bb, 0.f));
        }
        #pragma unroll
        for (int mt = 0; mt < 2; ++mt)
            #pragma unroll
            for (int nt = 0; nt < 8; ++nt) acc[mt][nt] = (v4f){0.f, 0.f, 0.f, 0.f};
        #pragma unroll
        for (int kk = 0; kk < 4; ++kk) {
            v8s a0 = *(const v8s*)&sB[wrow + l16][kk * 32 + quad * 8];
            v8s a1 = *(const v8s*)&sB[wrow + 16 + l16][kk * 32 + quad * 8];
            #pragma unroll
            for (int nt = 0; nt < 8; ++nt) {
                v8s b = *(const v8s*)(W2t + (nt * 16 + l16) * 128 + kk * 32 + quad * 8);
                acc[0][nt] = MFMA(a0, b, acc[0][nt]);
                acc[1][nt] = MFMA(a1, b, acc[1][nt]);
            }
        }
        #pragma unroll
        for (int mt = 0; mt < 2; ++mt)
            #pragma unroll
            for (int r = 0; r < 4; ++r) {
                float s = 0.f, qq = 0.f;
                #pragma unroll
                for (int nt = 0; nt < 8; ++nt) {
                    float u = acc[mt][nt][r] + sP[1][nt * 16 + l16];
                    acc[mt][nt][r] = u;
                    s += u; qq += u * u;
                }
                #pragma unroll
                for (int d = 1; d < 16; d <<= 1) {
                    s += __shfl_xor(s, d);
                    qq += __shfl_xor(qq, d);
                }
                float mn = s * (1.f / 128.f);
                float rs = rsqrtf(qq * (1.f / 128.f) - mn * mn + 1e-5f);
                #pragma unroll
                for (int nt = 0; nt < 8; ++nt) {
                    const int n = nt * 16 + l16;
                    macc[mt][nt][r] += fmaxf((acc[mt][nt][r] - mn) * rs * sP[2][n] + sP[3][n], 0.f);
                }
            }
        __syncthreads();
    }
    const int nn = num_node[g];
    #pragma unroll
    for (int mt = 0; mt < 2; ++mt)
        #pragma unroll
        for (int nt = 0; nt < 8; ++nt)
            #pragma unroll
            for (int r = 0; r < 4; ++r) {
                const int i = wrow + mt * 16 + quad * 4 + r;
                const int n = nt * 16 + l16;
                float v = (i >= nn) ? 0.f : macc[mt][nt][r] * (1.f / 6.f);
                zm[((size_t)(b_s * 128 + i)) * 128 + n] = __float2bfloat16(v);
            }
}

// ---------------- fused gl stage v2: SINGLE LDS buffer (v9 discipline).
// sHsT/sM aliased: h^T is rebuilt from hs_reg each layer, so after the spmv's
// B-reads the buffer is dead and M/T reuse it. LDS 73.7 -> 39.4 KB => 2+ blocks/CU.
// Extra barrier per layer: (A) after spmv reads, (B) after MM2 reads before h^T scatter.
__global__ __launch_bounds__(256) void k_gl_fused(
    const bf16* __restrict__ zm, const float* __restrict__ hb,
    const bf16* __restrict__ adjb,
    const bf16* __restrict__ s1Wt, const float* __restrict__ s1_b,
    const bf16* __restrict__ WTgl,
    const float* __restrict__ glb1, const float* __restrict__ glb2,
    const float* __restrict__ glg, const float* __restrict__ glbn,
    float* __restrict__ hsum)
{
    __shared__ __align__(16) short sB[128][136];    // h^T <-> M/T (aliased)  34.8 KB
    __shared__ float sP[9][128];                    //                          4.5 KB
    const int t = threadIdx.x;
    const int b_s = blockIdx.x;
    const int g = b_s >> 4;
    const int wave = t >> 6, lane = t & 63, quad = lane >> 4, l16 = lane & 15;
    const int wrow = wave << 5;

    for (int u = t; u < 9 * 128; u += 256) {
        const int a = u >> 7, n = u & 127;
        const float* src =
            (a == 0) ? glb1 : (a == 1) ? glb2 : (a == 2) ? glg : (a == 3) ? glbn :
            (a == 4) ? glb1 + 128 : (a == 5) ? glb2 + 128 : (a == 6) ? glg + 128 :
            (a == 7) ? glbn + 128 : s1_b;
        sP[a][n] = src[n];
    }

    v8s aA[2][4];
    {
        const bf16* ar = adjb + (size_t)g * 16384;
        #pragma unroll
        for (int mt = 0; mt < 2; ++mt)
            #pragma unroll
            for (int kk = 0; kk < 4; ++kk)
                aA[mt][kk] = *(const v8s*)(ar + (size_t)(wrow + mt * 16 + l16) * 128 + kk * 32 + quad * 8);
    }

    // ---- setmlp1: hs = relu(zm @ s1W + s1b) + h[g]  (A-operand straight from global) ----
    v4f acc[2][8];
    #pragma unroll
    for (int mt = 0; mt < 2; ++mt)
        #pragma unroll
        for (int nt = 0; nt < 8; ++nt) acc[mt][nt] = (v4f){0.f, 0.f, 0.f, 0.f};
    #pragma unroll
    for (int kk = 0; kk < 4; ++kk) {
        v8s a0 = *(const v8s*)(zm + ((size_t)(b_s * 128) + wrow + l16) * 128 + kk * 32 + quad * 8);
        v8s a1 = *(const v8s*)(zm + ((size_t)(b_s * 128) + wrow + 16 + l16) * 128 + kk * 32 + quad * 8);
        #pragma unroll
        for (int nt = 0; nt < 8; ++nt) {
            v8s b = *(const v8s*)(s1Wt + (nt * 16 + l16) * 128 + kk * 32 + quad * 8);
            acc[0][nt] = MFMA(a0, b, acc[0][nt]);
            acc[1][nt] = MFMA(a1, b, acc[1][nt]);
        }
    }
    __syncthreads();                 // sP visible
    float hs_reg[2][8][4];
    #pragma unroll
    for (int mt = 0; mt < 2; ++mt)
        #pragma unroll
        for (int nt = 0; nt < 8; ++nt)
            #pragma unroll
            for (int r = 0; r < 4; ++r) {
                const int i = wrow + mt * 16 + quad * 4 + r;
                const int n = nt * 16 + l16;
                float v = fmaxf(acc[mt][nt][r] + sP[8][n], 0.f);
                v += hb[((size_t)(g * 128 + i)) * 128 + n];
                hs_reg[mt][nt][r] = v;
                sB[n][i] = f2s(v);
            }
    __syncthreads();                 // h^T complete

    for (int l = 0; l < 2; ++l) {
        const bf16* W1t = WTgl + (size_t)(2 * l) * 16384;
        const bf16* W2t = WTgl + (size_t)(2 * l + 1) * 16384;
        // spmv: M = A @ Hs (B-frags from sB rows, cross-wave)
        #pragma unroll
        for (int mt = 0; mt < 2; ++mt)
            #pragma unroll
            for (int nt = 0; nt < 8; ++nt) acc[mt][nt] = (v4f){0.f, 0.f, 0.f, 0.f};
        #pragma unroll
        for (int kk = 0; kk < 4; ++kk)
            #pragma unroll
            for (int nt = 0; nt < 8; ++nt) {
                v8s b = *(const v8s*)&sB[nt * 16 + l16][kk * 32 + quad * 8];
                acc[0][nt] = MFMA(aA[0][kk], b, acc[0][nt]);
                acc[1][nt] = MFMA(aA[1][kk], b, acc[1][nt]);
            }
        __syncthreads();             // (A) all spmv reads done; sB reusable as M/T
        #pragma unroll
        for (int nt = 0; nt < 8; ++nt)
            #pragma unroll
            for (int mt = 0; mt < 2; ++mt)
                #pragma unroll
                for (int r = 0; r < 4; ++r)
                    sB[wrow + mt * 16 + quad * 4 + r][nt * 16 + l16] = f2s(acc[mt][nt][r]);
        // MM1 (wave-own rows)
        #pragma unroll
        for (int mt = 0; mt < 2; ++mt)
            #pragma unroll
            for (int nt = 0; nt < 8; ++nt) acc[mt][nt] = (v4f){0.f, 0.f, 0.f, 0.f};
        #pragma unroll
        for (int kk = 0; kk < 4; ++kk) {
            v8s a0 = *(const v8s*)&sB[wrow + l16][kk * 32 + quad * 8];
            v8s a1 = *(const v8s*)&sB[wrow + 16 + l16][kk * 32 + quad * 8];
            #pragma unroll
            for (int nt = 0; nt < 8; ++nt) {
                v8s b = *(const v8s*)(W1t + (nt * 16 + l16) * 128 + kk * 32 + quad * 8);
                acc[0][nt] = MFMA(a0, b, acc[0][nt]);
                acc[1][nt] = MFMA(a1, b, acc[1][nt]);
            }
        }
        #pragma unroll
        for (int nt = 0; nt < 8; ++nt) {
            float bb = sP[4 * l + 0][nt * 16 + l16];
            #pragma unroll
            for (int mt = 0; mt < 2; ++mt)
                #pragma unroll
                for (int r = 0; r < 4; ++r)
                    sB[wrow + mt * 16 + quad * 4 + r][nt * 16 + l16] = f2s(fmaxf(acc[mt][nt][r] + bb, 0.f));
        }
        // MM2 (wave-own rows)
        #pragma unroll
        for (int mt = 0; mt < 2; ++mt)
            #pragma unroll
            for (int nt = 0; nt < 8; ++nt) acc[mt][nt] = (v4f){0.f, 0.f, 0.f, 0.f};
        #pragma unroll
        for (int kk = 0; kk < 4; ++kk) {
            v8s a0 = *(const v8s*)&sB[wrow + l16][kk * 32 + quad * 8];
            v8s a1 = *(const v8s*)&sB[wrow + 16 + l16][kk * 32 + quad * 8];
            #pragma unroll
            for (int nt = 0; nt < 8; ++nt) {
                v8s b = *(const v8s*)(W2t + (nt * 16 + l16) * 128 + kk * 32 + quad * 8);
                acc[0][nt] = MFMA(a0, b, acc[0][nt]);
                acc[1][nt] = MFMA(a1, b, acc[1][nt]);
            }
        }
        __syncthreads();             // (B) all MM2 reads done before h^T scatter
        // LN epilogue: hs_reg update + h^T scatter
        #pragma unroll
        for (int mt = 0; mt < 2; ++mt)
            #pragma unroll
            for (int r = 0; r < 4; ++r) {
                float s = 0.f, qq = 0.f;
                #pragma unroll
                for (int nt = 0; nt < 8; ++nt) {
                    float u = acc[mt][nt][r] + sP[4 * l + 1][nt * 16 + l16];
                    acc[mt][nt][r] = u;
                    s += u; qq += u * u;
                }
                #pragma unroll
                for (int d = 1; d < 16; d <<= 1) {
                    s += __shfl_xor(s, d);
                    qq += __shfl_xor(qq, d);
                }
                float mn = s * (1.f / 128.f);
                float rs = rsqrtf(qq * (1.f / 128.f) - mn * mn + 1e-5f);
                const int i = wrow + mt * 16 + quad * 4 + r;
                #pragma unroll
                for (int nt = 0; nt < 8; ++nt) {
                    const int n = nt * 16 + l16;
                    float v = fmaxf((acc[mt][nt][r] - mn) * rs * sP[4 * l + 2][n] + sP[4 * l + 3][n], 0.f);
                    float h2 = hs_reg[mt][nt][r] + v;
                    hs_reg[mt][nt][r] = h2;
                    sB[n][i] = f2s(h2);
                }
            }
        __syncthreads();             // (C) h^T complete
    }

    // ---- node-sum: hsum[b_s][n] = sum_i hs[i][n] (sB dead, reuse as f32 scratch) ----
    float* sRedf = (float*)&sB[0][0];
    #pragma unroll
    for (int nt = 0; nt < 8; ++nt) {
        float part = 0.f;
        #pragma unroll
        for (int mt = 0; mt < 2; ++mt)
            #pragma unroll
            for (int r = 0; r < 4; ++r) part += hs_reg[mt][nt][r];
        sRedf[(wave * 4 + quad) * 128 + nt * 16 + l16] = part;
    }
    __syncthreads();
    if (t < 128) {
        float s = 0.f;
        #pragma unroll
        for (int r = 0; r < 16; ++r) s += sRedf[r * 128 + t];
        hsum[(size_t)b_s * 128 + t] = s;
    }
}

// ---------------- fused tail: setmlp2 + maxpool + setmlp3 + out proj, 1 block/graph ----------------
__global__ __launch_bounds__(128) void k_tail(const float* __restrict__ hsum,
    const float* __restrict__ s2W, const float* __restrict__ s2b,
    const float* __restrict__ rW1, const float* __restrict__ rb1,
    const float* __restrict__ rW2, const float* __restrict__ rb2,
    const float* __restrict__ rg, const float* __restrict__ rbn,
    const float* __restrict__ outW, const float* __restrict__ outb,
    float* __restrict__ out)
{
    __shared__ float sA[16][136];
    __shared__ float sV[128];
    __shared__ float red[128];
    const int g = blockIdx.x, hd = threadIdx.x;
    // setmlp2 over this graph's 16 subgraph rows
    #pragma unroll
    for (int r = 0; r < 16; ++r) sA[r][hd] = hsum[((size_t)(g * 16 + r)) * 128 + hd];
    __syncthreads();
    float acc[16];
    #pragma unroll
    for (int r = 0; r < 16; ++r) acc[r] = s2b[hd];
    for (int k = 0; k < 128; k += 4) {
        float w0 = s2W[(k+0)*128+hd], w1 = s2W[(k+1)*128+hd], w2 = s2W[(k+2)*128+hd], w3 = s2W[(k+3)*128+hd];
        #pragma unroll
        for (int r = 0; r < 16; ++r) {
            float4 a = *(const float4*)&sA[r][k];
            acc[r] = fmaf(a.x, w0, acc[r]); acc[r] = fmaf(a.y, w1, acc[r]);
            acc[r] = fmaf(a.z, w2, acc[r]); acc[r] = fmaf(a.w, w3, acc[r]);
        }
    }
    // maxpool (relu is monotone: max of relu = relu of max applied elementwise)
    float pool = 0.f;  // relu(...) >= 0, so 0 is a safe floor... use -inf then relu
    pool = -INFINITY;
    #pragma unroll
    for (int r = 0; r < 16; ++r) pool = fmaxf(pool, fmaxf(acc[r], 0.f));
    sV[hd] = pool;
    __syncthreads();
    // setmlp3: t1 = relu(pool @ rW1 + rb1)
    float t1 = rb1[hd];
    for (int k = 0; k < 128; ++k) t1 = fmaf(sV[k], rW1[k * 128 + hd], t1);
    t1 = fmaxf(t1, 0.f);
    red[hd] = t1;
    __syncthreads();
    float u = rb2[hd];
    for (int k = 0; k < 128; ++k) u = fmaf(red[k], rW2[k * 128 + hd], u);
    // LN across 128 (parallel reduce; reuse sA rows 0 and 2)
    float* rs1 = (float*)&sA[0][0];
    float* rs2 = (float*)&sA[2][0];
    rs1[hd] = u; rs2[hd] = u * u;
    __syncthreads();
    for (int s = 64; s > 0; s >>= 1) {
        if (hd < s) { rs1[hd] += rs1[hd + s]; rs2[hd] += rs2[hd + s]; }
        __syncthreads();
    }
    float mn = rs1[0] * (1.f / 128.f);
    float var = rs2[0] * (1.f / 128.f) - mn * mn;
    float rstd = rsqrtf(var + 1e-5f);
    float p2 = fmaxf((u - mn) * rstd * rg[hd] + rbn[hd], 0.f) + sV[hd];
    __syncthreads();
    red[hd] = p2 * outW[hd];
    __syncthreads();
    for (int s = 64; s > 0; s >>= 1) {
        if (hd < s) red[hd] += red[hd + s];
        __syncthreads();
    }
    if (hd == 0) out[g] = red[0] + outb[0];
}

extern "C" void kernel_launch(void* const* d_in, const int* in_sizes, int n_in,
                              void* d_out, int out_size, void* d_ws, size_t ws_size,
                              hipStream_t stream)
{
    (void)in_sizes; (void)n_in; (void)out_size; (void)ws_size;
    const float* x     = (const float*)d_in[0];
    const float* adj   = (const float*)d_in[1];
    const float* idemb = (const float*)d_in[2];
    const float* in_W1 = (const float*)d_in[3];
    const float* in_b1 = (const float*)d_in[4];
    const float* in_W2 = (const float*)d_in[5];
    const float* in_b2 = (const float*)d_in[6];
    const float* in_g  = (const float*)d_in[7];
    const float* in_bn = (const float*)d_in[8];
    const float* gW1   = (const float*)d_in[9];
    const float* gb1   = (const float*)d_in[10];
    const float* gW2   = (const float*)d_in[11];
    const float* gb2   = (const float*)d_in[12];
    const float* gg    = (const float*)d_in[13];
    const float* gbn   = (const float*)d_in[14];
    const float* iW1   = (const float*)d_in[15];
    const float* ib1   = (const float*)d_in[16];
    const float* iW2   = (const float*)d_in[17];
    const float* ib2   = (const float*)d_in[18];
    const float* ig    = (const float*)d_in[19];
    const float* ibn   = (const float*)d_in[20];
    const float* glW1  = (const float*)d_in[21];
    const float* glb1  = (const float*)d_in[22];
    const float* glW2  = (const float*)d_in[23];
    const float* glb2  = (const float*)d_in[24];
    const float* glg   = (const float*)d_in[25];
    const float* glbn  = (const float*)d_in[26];
    const float* s1_W  = (const float*)d_in[27];
    const float* s1_b  = (const float*)d_in[28];
    const float* s2_W  = (const float*)d_in[29];
    const float* s2_b  = (const float*)d_in[30];
    const float* rW1   = (const float*)d_in[31];
    const float* rb1   = (const float*)d_in[32];
    const float* rW2   = (const float*)d_in[33];
    const float* rb2   = (const float*)d_in[34];
    const float* rg    = (const float*)d_in[35];
    const float* rbn   = (const float*)d_in[36];
    const float* out_W = (const float*)d_in[37];
    const float* out_b = (const float*)d_in[38];
    const int* subgs   = (const int*)d_in[39];
    const int* num_node= (const int*)d_in[41];
    const int* allperm = (const int*)d_in[42];

    // ---- workspace layout (unchanged budget) ----
    const size_t MB_ = (size_t)512 * 128 * P_ * H_ * 2;        // 100,663,296: z2t
    char* w = (char*)d_ws;
    bf16*  mz     = (bf16*)(w);                                // region A: z2t
    bf16*  s1Wt   = (bf16*)(w + 33554432ull);                  // region A reuse (post-id2): s1_W^T bf16
    bf16*  zm     = (bf16*)(w + MB_);                          // (512,128,128) bf16 = 16.8 MB
    bf16*  WT     = (bf16*)(w + MB_ + 16777216ull);            // 8 x (128x128) bf16 transposed
    char*  wc     = w + MB_ + 16777216ull + 262144ull;
    float* hb     = (float*)(wc);                              // h (32,128,128) f32  2 MB
    bf16*  adjb   = (bf16*)(wc + 2097152ull);                  // 1 MB
    bf16*  WT2    = (bf16*)(wc + 3145728ull);                  // 8 x 32KB = 256 KB
    float* hsum   = (float*)(wc + 4194304ull);                 // (512,128)
    float* degf   = (float*)(wc + 4964352ull);                 // 4096 f32
    float* outp   = (float*)d_out;

    // prep: degf + transposed bf16 weights + adjb
    k_deg<<<4096, 128, 0, stream>>>(adj, degf);
    k_wt8<<<1024, 128, 0, stream>>>(iW1, iW2, iW1 + 16384, iW2 + 16384,
                                    glW1, glW2, glW1 + 16384, glW2 + 16384, WT);
    k_wt8<<<1024, 128, 0, stream>>>(in_W2, gW1, gW2, gW1 + 16384,
                                    gW2 + 16384, gW1 + 32768, gW2 + 32768, in_W2, WT2);
    k_adjb<<<4096, 128, 0, stream>>>(adj, adjb);

    // h pipeline fused: input embed + 3 g-layers -> hb
    k_h_fused<<<32, 256, 0, stream>>>(x, adjb, in_W1, in_b1,
        WT2, in_b2, in_g, in_bn,
        WT2 + 16384, gb1, gb2, gg, gbn, hb);

    // ID layer 1 FUSED (single-buffer): m in-LDS -> MFMA MLP -> z2t
    k_id1_fused<<<3072, 256, 0, stream>>>(adj, degf, subgs, allperm, idemb, mz,
        WT, ib1, WT + 16384, ib2, ig, ibn);

    // ID layer 2 v9 -> zm
    k_id2_v9<<<512, 256, 0, stream>>>(mz, zm, adjb, num_node, subgs, allperm, idemb,
        WT + 2 * 16384, ib1 + 128, WT + 3 * 16384, ib2 + 128, ig + 128, ibn + 128);

    // s1_W^T (into region A — z2t is dead now)
    k_wt1<<<128, 128, 0, stream>>>(s1_W, s1Wt);

    // fused gl v2 (single-buffer): setmlp1 + 2 gl layers + node-sum -> hsum
    k_gl_fused<<<512, 256, 0, stream>>>(zm, hb, adjb, s1Wt, s1_b,
        WT + 4 * 16384, glb1, glb2, glg, glbn, hsum);

    // fused tail: setmlp2 + maxpool + setmlp3 + out proj
    k_tail<<<32, 128, 0, stream>>>(hsum, s2_W, s2_b, rW1, rb1, rW2, rb2,
        rg, rbn, out_W, out_b, outp);
}